// Round 4
// baseline (148.600 us; speedup 1.0000x reference)
//
#include <hip/hip_runtime.h>

// SNN binary classifier, fused single kernel. B=4096, D=256, H=512, O=2, T=100.
// Block = 256 threads (4 waves) handles BM=4 batch rows; grid = 1024 = 4 blocks/CU
// -> 16 waves/CU = 4 waves/SIMD (latency hiding), with __launch_bounds__(256,1):
// empirically arg2>=2 makes the backend clamp to 32 VGPRs and destroy the
// phase-1/phase-2 register tiling (R2/R3 regressions); (256,1) gave 84 VGPRs (R1).
//   Phase 1: h1 = x @ W1^T + b1 into LDS. Thread t computes h-cols 2t,2t+1 for
//            4 rows; per-(row,col) k-order bit-identical to R1's passing kernel.
//   Phase 2: LIF recurrence. 1 row per wave, 64 lanes, 8 h-elems/lane.
//            Per-step 64-lane reduce: 4x DPP row_ror + row_bcast15 + row_bcast31
//            (pure VALU, no LDS). Lane 48 holds the full sum and writes.

#define BM 4
#define LDS_H_STRIDE 520   // 512 + 8 pad

template <int CTRL>
__device__ __forceinline__ float dpp_add(float v) {
    int x = __builtin_amdgcn_update_dpp(0, __builtin_bit_cast(int, v),
                                        CTRL, 0xF, 0xF, false);
    return v + __builtin_bit_cast(float, x);
}

__global__ __launch_bounds__(256, 1) void snn_fused_kernel(
    const float* __restrict__ x,   // [4096,256]
    const float* __restrict__ W1,  // [512,256]
    const float* __restrict__ b1,  // [512]
    const float* __restrict__ W2,  // [2,512]
    const float* __restrict__ b2,  // [2]
    const int* __restrict__ tsp,   // [1]
    float* __restrict__ out)       // [4096,2]
{
    __shared__ float xs[BM * 256];            // 4 KiB
    __shared__ float h1s[BM * LDS_H_STRIDE];  // ~8.3 KiB

    const int tid  = threadIdx.x;
    const int row0 = blockIdx.x * BM;

    // ---- stage x rows (coalesced float4, 4 rows = 256 float4) ----
    ((float4*)xs)[tid] = ((const float4*)(x + (size_t)row0 * 256))[tid];
    __syncthreads();

    // ---- Phase 1: 2 h-columns x 4 rows per thread ----
    {
        const int h0 = tid * 2;
        float acc0[BM], acc1[BM];
        const float bia0 = b1[h0], bia1 = b1[h0 + 1];
        #pragma unroll
        for (int b = 0; b < BM; ++b) { acc0[b] = bia0; acc1[b] = bia1; }

        const float4* w0v = (const float4*)(W1 + (size_t)h0 * 256);
        const float4* w1v = (const float4*)(W1 + (size_t)(h0 + 1) * 256);
        const float4* xsv = (const float4*)xs;

        float4 wa = w0v[0], wb = w1v[0];
        #pragma unroll 1
        for (int k4 = 0; k4 < 64; ++k4) {
            const int kn = (k4 < 63) ? k4 + 1 : 63;   // prefetch next W1 chunk
            float4 wan = w0v[kn], wbn = w1v[kn];
            float4 xv[BM];
            #pragma unroll
            for (int b = 0; b < BM; ++b) xv[b] = xsv[b * 64 + k4]; // broadcast
            #pragma unroll
            for (int b = 0; b < BM; ++b) {
                acc0[b] = fmaf(xv[b].x, wa.x, acc0[b]);
                acc0[b] = fmaf(xv[b].y, wa.y, acc0[b]);
                acc0[b] = fmaf(xv[b].z, wa.z, acc0[b]);
                acc0[b] = fmaf(xv[b].w, wa.w, acc0[b]);
                acc1[b] = fmaf(xv[b].x, wb.x, acc1[b]);
                acc1[b] = fmaf(xv[b].y, wb.y, acc1[b]);
                acc1[b] = fmaf(xv[b].z, wb.z, acc1[b]);
                acc1[b] = fmaf(xv[b].w, wb.w, acc1[b]);
            }
            wa = wan; wb = wbn;
        }
        #pragma unroll
        for (int b = 0; b < BM; ++b) {
            float2* dst = (float2*)&h1s[b * LDS_H_STRIDE + h0];
            *dst = make_float2(acc0[b], acc1[b]);
        }
    }
    __syncthreads();

    // ---- Phase 2: LIF recurrence, 1 row per wave ----
    {
        const int l   = tid & 63;
        const int wid = tid >> 6;          // 0..3 = local row
        const int row = row0 + wid;

        float hv[8], w0r[8], w1r[8], mem[8];
        #pragma unroll
        for (int j = 0; j < 8; ++j) {
            const int h = l + j * 64;      // consecutive lanes -> consecutive LDS
            hv[j]  = h1s[wid * LDS_H_STRIDE + h];
            w0r[j] = W2[h];
            w1r[j] = W2[512 + h];
            mem[j] = 0.0f;
        }
        const float bb0 = b2[0], bb1 = b2[1];
        const int   T   = tsp[0];

        float c0 = 0.0f, c1 = 0.0f;
        for (int t = 0; t < T; ++t) {
            float a0 = 0.0f, a1 = 0.0f, a0b = 0.0f, a1b = 0.0f;
            #pragma unroll
            for (int j = 0; j < 8; j += 2) {
                // membrane update non-fused to match reference algebra exactly
                float m0 = __fadd_rn(__fmul_rn(0.9f, mem[j]),     hv[j]);
                float m1 = __fadd_rn(__fmul_rn(0.9f, mem[j + 1]), hv[j + 1]);
                float s0 = (m0 > 1.0f) ? 1.0f : 0.0f;
                float s1 = (m1 > 1.0f) ? 1.0f : 0.0f;
                mem[j]     = m0 - s0;
                mem[j + 1] = m1 - s1;
                a0  = fmaf(s0, w0r[j],     a0);
                a1  = fmaf(s0, w1r[j],     a1);
                a0b = fmaf(s1, w0r[j + 1], a0b);
                a1b = fmaf(s1, w1r[j + 1], a1b);
            }
            a0 += a0b; a1 += a1b;
            // 64-lane reduce, pure VALU DPP:
            a0 = dpp_add<0x121>(a0); a1 = dpp_add<0x121>(a1);  // ror 1
            a0 = dpp_add<0x122>(a0); a1 = dpp_add<0x122>(a1);  // ror 2
            a0 = dpp_add<0x124>(a0); a1 = dpp_add<0x124>(a1);  // ror 4
            a0 = dpp_add<0x128>(a0); a1 = dpp_add<0x128>(a1);  // ror 8
            a0 = dpp_add<0x142>(a0); a1 = dpp_add<0x142>(a1);  // row_bcast15
            a0 = dpp_add<0x143>(a0); a1 = dpp_add<0x143>(a1);  // row_bcast31
            // lanes 48..63 now hold the full 512-sum
            c0 += ((a0 + bb0) > 0.0f) ? 1.0f : 0.0f;
            c1 += ((a1 + bb1) > 0.0f) ? 1.0f : 0.0f;
        }

        if (l == 48) {
            const float ft = (float)T;
            float2* dst = (float2*)(out + (size_t)row * 2);
            *dst = make_float2(c0 / ft, c1 / ft);
        }
    }
}

extern "C" void kernel_launch(void* const* d_in, const int* in_sizes, int n_in,
                              void* d_out, int out_size, void* d_ws, size_t ws_size,
                              hipStream_t stream) {
    const float* x   = (const float*)d_in[0];
    const float* W1  = (const float*)d_in[1];
    const float* b1  = (const float*)d_in[2];
    const float* W2  = (const float*)d_in[3];
    const float* b2  = (const float*)d_in[4];
    const int*   tsp = (const int*)d_in[5];
    float*       out = (float*)d_out;

    const int B = in_sizes[0] / 256;          // 4096
    snn_fused_kernel<<<dim3(B / BM), dim3(256), 0, stream>>>(
        x, W1, b1, W2, b2, tsp, out);
}

// Round 5
// 143.089 us; speedup vs baseline: 1.0385x; 1.0385x over previous
//
#include <hip/hip_runtime.h>

// SNN binary classifier, fused single kernel. B=4096, D=256, H=512, O=2, T=100.
// Block = 256 threads (4 waves), BM=4 rows/block, grid = 1024 = exactly 4
// blocks/CU (16 waves/CU = 4 waves/SIMD, no tail).
//
// R2-R4 lesson: the backend clamped this kernel to 32 VGPRs (vs R1's 84) and
// demoted the loop-invariant phase-2 state (hv/w0r/w1r) to per-iteration
// LDS/L2 reloads -> 163us, VALUBusy 40%. Countermeasures here:
//   (1) asm-pin the persistent arrays into VGPRs inside both hot loops
//       (empty asm with "+v" constraints each iteration),
//   (2) LDS padded to 38.9KB (stride 2176) -> occupancy heuristic sees
//       4 blocks/CU max, same LDS class as the good R1 codegen.
// Phase-1 per-(row,col) k-order is bit-identical to R1/R3 -> same h1/s1
// trajectories, absmax unchanged.

#define BM 4
#define LDS_H_STRIDE 2176   // 512 cols + big pad: LDS sizing lever (38.9 KB total)

template <int CTRL>
__device__ __forceinline__ float dpp_add(float v) {
    int x = __builtin_amdgcn_update_dpp(0, __builtin_bit_cast(int, v),
                                        CTRL, 0xF, 0xF, false);
    return v + __builtin_bit_cast(float, x);
}

__global__ __launch_bounds__(256, 1) void snn_fused_kernel(
    const float* __restrict__ x,   // [4096,256]
    const float* __restrict__ W1,  // [512,256]
    const float* __restrict__ b1,  // [512]
    const float* __restrict__ W2,  // [2,512]
    const float* __restrict__ b2,  // [2]
    const int* __restrict__ tsp,   // [1]
    float* __restrict__ out)       // [4096,2]
{
    __shared__ float xs[BM * 256];            // 4 KiB
    __shared__ float h1s[BM * LDS_H_STRIDE];  // 34.8 KiB

    const int tid  = threadIdx.x;
    const int row0 = blockIdx.x * BM;

    // ---- stage x rows (coalesced float4, 4 rows = 256 float4) ----
    ((float4*)xs)[tid] = ((const float4*)(x + (size_t)row0 * 256))[tid];
    __syncthreads();

    // ---- Phase 1: 2 h-columns x 4 rows per thread ----
    {
        const int h0 = tid * 2;
        float acc0[BM], acc1[BM];
        const float bia0 = b1[h0], bia1 = b1[h0 + 1];
        #pragma unroll
        for (int b = 0; b < BM; ++b) { acc0[b] = bia0; acc1[b] = bia1; }

        const float4* w0v = (const float4*)(W1 + (size_t)h0 * 256);
        const float4* w1v = (const float4*)(W1 + (size_t)(h0 + 1) * 256);
        const float4* xsv = (const float4*)xs;

        float4 wa = w0v[0], wb = w1v[0];
        #pragma unroll 1
        for (int k4 = 0; k4 < 64; ++k4) {
            const int kn = (k4 < 63) ? k4 + 1 : 63;   // prefetch next W1 chunk
            float4 wan = w0v[kn], wbn = w1v[kn];
            float4 xv[BM];
            #pragma unroll
            for (int b = 0; b < BM; ++b) xv[b] = xsv[b * 64 + k4]; // broadcast
            #pragma unroll
            for (int b = 0; b < BM; ++b) {
                acc0[b] = fmaf(xv[b].x, wa.x, acc0[b]);
                acc0[b] = fmaf(xv[b].y, wa.y, acc0[b]);
                acc0[b] = fmaf(xv[b].z, wa.z, acc0[b]);
                acc0[b] = fmaf(xv[b].w, wa.w, acc0[b]);
                acc1[b] = fmaf(xv[b].x, wb.x, acc1[b]);
                acc1[b] = fmaf(xv[b].y, wb.y, acc1[b]);
                acc1[b] = fmaf(xv[b].z, wb.z, acc1[b]);
                acc1[b] = fmaf(xv[b].w, wb.w, acc1[b]);
            }
            wa = wan; wb = wbn;
            // pin accumulators in VGPRs (forbid demotion/remat)
            asm volatile("" : "+v"(acc0[0]), "+v"(acc0[1]), "+v"(acc0[2]), "+v"(acc0[3]),
                             "+v"(acc1[0]), "+v"(acc1[1]), "+v"(acc1[2]), "+v"(acc1[3]));
        }
        #pragma unroll
        for (int b = 0; b < BM; ++b) {
            float2* dst = (float2*)&h1s[b * LDS_H_STRIDE + h0];
            *dst = make_float2(acc0[b], acc1[b]);
        }
    }
    __syncthreads();

    // ---- Phase 2: LIF recurrence, 1 row per wave ----
    {
        const int l   = tid & 63;
        const int wid = tid >> 6;          // 0..3 = local row
        const int row = row0 + wid;

        float hv[8], w0r[8], w1r[8], mem[8];
        #pragma unroll
        for (int j = 0; j < 8; ++j) {
            const int h = l + j * 64;      // consecutive lanes -> consecutive LDS
            hv[j]  = h1s[wid * LDS_H_STRIDE + h];
            w0r[j] = W2[h];
            w1r[j] = W2[512 + h];
            mem[j] = 0.0f;
        }
        const float bb0 = b2[0], bb1 = b2[1];
        const int   T   = tsp[0];

        float c0 = 0.0f, c1 = 0.0f;
        for (int t = 0; t < T; ++t) {
            float a0 = 0.0f, a1 = 0.0f, a0b = 0.0f, a1b = 0.0f;
            #pragma unroll
            for (int j = 0; j < 8; j += 2) {
                // membrane update non-fused to match reference algebra exactly
                float m0 = __fadd_rn(__fmul_rn(0.9f, mem[j]),     hv[j]);
                float m1 = __fadd_rn(__fmul_rn(0.9f, mem[j + 1]), hv[j + 1]);
                float s0 = (m0 > 1.0f) ? 1.0f : 0.0f;
                float s1 = (m1 > 1.0f) ? 1.0f : 0.0f;
                mem[j]     = m0 - s0;
                mem[j + 1] = m1 - s1;
                a0  = fmaf(s0, w0r[j],     a0);
                a1  = fmaf(s0, w1r[j],     a1);
                a0b = fmaf(s1, w0r[j + 1], a0b);
                a1b = fmaf(s1, w1r[j + 1], a1b);
            }
            a0 += a0b; a1 += a1b;
            // 64-lane reduce, pure VALU DPP:
            a0 = dpp_add<0x121>(a0); a1 = dpp_add<0x121>(a1);  // ror 1
            a0 = dpp_add<0x122>(a0); a1 = dpp_add<0x122>(a1);  // ror 2
            a0 = dpp_add<0x124>(a0); a1 = dpp_add<0x124>(a1);  // ror 4
            a0 = dpp_add<0x128>(a0); a1 = dpp_add<0x128>(a1);  // ror 8
            a0 = dpp_add<0x142>(a0); a1 = dpp_add<0x142>(a1);  // row_bcast15
            a0 = dpp_add<0x143>(a0); a1 = dpp_add<0x143>(a1);  // row_bcast31
            // lanes 48..63 now hold the full 512-sum
            c0 += ((a0 + bb0) > 0.0f) ? 1.0f : 0.0f;
            c1 += ((a1 + bb1) > 0.0f) ? 1.0f : 0.0f;

            // pin loop-resident state in VGPRs (forbid per-iteration reloads)
            asm volatile("" : "+v"(hv[0]),  "+v"(hv[1]),  "+v"(hv[2]),  "+v"(hv[3]),
                             "+v"(hv[4]),  "+v"(hv[5]),  "+v"(hv[6]),  "+v"(hv[7]));
            asm volatile("" : "+v"(w0r[0]), "+v"(w0r[1]), "+v"(w0r[2]), "+v"(w0r[3]),
                             "+v"(w0r[4]), "+v"(w0r[5]), "+v"(w0r[6]), "+v"(w0r[7]));
            asm volatile("" : "+v"(w1r[0]), "+v"(w1r[1]), "+v"(w1r[2]), "+v"(w1r[3]),
                             "+v"(w1r[4]), "+v"(w1r[5]), "+v"(w1r[6]), "+v"(w1r[7]));
        }

        if (l == 48) {
            const float ft = (float)T;
            float2* dst = (float2*)(out + (size_t)row * 2);
            *dst = make_float2(c0 / ft, c1 / ft);
        }
    }
}

extern "C" void kernel_launch(void* const* d_in, const int* in_sizes, int n_in,
                              void* d_out, int out_size, void* d_ws, size_t ws_size,
                              hipStream_t stream) {
    const float* x   = (const float*)d_in[0];
    const float* W1  = (const float*)d_in[1];
    const float* b1  = (const float*)d_in[2];
    const float* W2  = (const float*)d_in[3];
    const float* b2  = (const float*)d_in[4];
    const int*   tsp = (const int*)d_in[5];
    float*       out = (float*)d_out;

    const int B = in_sizes[0] / 256;          // 4096
    snn_fused_kernel<<<dim3(B / BM), dim3(256), 0, stream>>>(
        x, W1, b1, W2, b2, tsp, out);
}

// Round 6
// 117.572 us; speedup vs baseline: 1.2639x; 1.2170x over previous
//
#include <hip/hip_runtime.h>

// SNN binary classifier, two-kernel split. B=4096, D=256, H=512, O=2, T=100.
//
// R1-R5 lesson (all data points fit): the AMDGPU backend derives its VGPR
// budget from LDS-implied max occupancy (512 VGPR/SIMD / target waves), and
// __launch_bounds__ arg2 is only a MINIMUM — small-LDS kernels get squeezed
// to 32 VGPRs with loop-state demoted to reload code (R2-R4: 163 us).
// Fix: __attribute__((amdgpu_waves_per_eu(4,4))) caps the target at 4
// waves/SIMD -> 128-VGPR budget -> natural codegen.
//
// Kernel A: h1 = x@W1^T + b1 -> d_ws. 256 thr, 32x64 tile, x-tile in LDS,
//   4 rows x 2 cols per thread. Per-(row,col) k-order bit-identical to the
//   passing R1 kernel (bias first, k ascending by float4 lanes).
// Kernel B: LIF recurrence from d_ws. Zero LDS, 1 row/wave, 8 h-elems/lane
//   (32-float loop state, register-resident), 6-stage DPP reduce
//   (row_ror 1/2/4/8 + row_bcast15 + row_bcast31; lane 48 writes).
// Fallback: proven R1 fused kernel if ws_size < 8 MB.

template <int CTRL>
__device__ __forceinline__ float dpp_add(float v) {
    int x = __builtin_amdgcn_update_dpp(0, __builtin_bit_cast(int, v),
                                        CTRL, 0xF, 0xF, false);
    return v + __builtin_bit_cast(float, x);
}

// ---------------- Kernel A: fc1 GEMM ----------------
#define AM 32
#define AN 64

__global__ __launch_bounds__(256)
__attribute__((amdgpu_waves_per_eu(4, 4)))
void snn_fc1_kernel(const float* __restrict__ x,   // [4096,256]
                    const float* __restrict__ W1,  // [512,256]
                    const float* __restrict__ b1,  // [512]
                    float* __restrict__ h1ws)      // [4096,512]
{
    __shared__ float xs[AM * 256];   // 32 KiB

    const int tid  = threadIdx.x;
    const int row0 = blockIdx.x * AM;
    const int col0 = blockIdx.y * AN;

    // stage 32 x-rows (2048 float4, 8 per thread, coalesced)
    {
        const float4* xg  = (const float4*)(x + (size_t)row0 * 256);
        float4*       xsv = (float4*)xs;
        #pragma unroll
        for (int i = 0; i < 8; ++i)
            xsv[i * 256 + tid] = xg[i * 256 + tid];
    }
    __syncthreads();

    const int tx = tid & 31;          // col pair 0..31
    const int ty = tid >> 5;          // row group 0..7
    const int c0 = col0 + tx * 2;
    const int r0 = ty * 4;

    float acc0[4], acc1[4];
    const float bia0 = b1[c0], bia1 = b1[c0 + 1];
    #pragma unroll
    for (int r = 0; r < 4; ++r) { acc0[r] = bia0; acc1[r] = bia1; }

    const float4* w0v = (const float4*)(W1 + (size_t)c0 * 256);
    const float4* w1v = (const float4*)(W1 + (size_t)(c0 + 1) * 256);
    const float4* xsv = (const float4*)xs;

    float4 wa = w0v[0], wb = w1v[0];
    #pragma unroll 1
    for (int k4 = 0; k4 < 64; ++k4) {
        const int kn = (k4 < 63) ? k4 + 1 : 63;     // prefetch next W1 chunk
        float4 wan = w0v[kn], wbn = w1v[kn];
        float4 xv[4];
        #pragma unroll
        for (int r = 0; r < 4; ++r) xv[r] = xsv[(r0 + r) * 64 + k4]; // broadcast
        #pragma unroll
        for (int r = 0; r < 4; ++r) {
            acc0[r] = fmaf(xv[r].x, wa.x, acc0[r]);
            acc0[r] = fmaf(xv[r].y, wa.y, acc0[r]);
            acc0[r] = fmaf(xv[r].z, wa.z, acc0[r]);
            acc0[r] = fmaf(xv[r].w, wa.w, acc0[r]);
            acc1[r] = fmaf(xv[r].x, wb.x, acc1[r]);
            acc1[r] = fmaf(xv[r].y, wb.y, acc1[r]);
            acc1[r] = fmaf(xv[r].z, wb.z, acc1[r]);
            acc1[r] = fmaf(xv[r].w, wb.w, acc1[r]);
        }
        wa = wan; wb = wbn;
    }
    #pragma unroll
    for (int r = 0; r < 4; ++r) {
        float2* dst = (float2*)&h1ws[(size_t)(row0 + r0 + r) * 512 + c0];
        *dst = make_float2(acc0[r], acc1[r]);
    }
}

// ---------------- Kernel B: LIF recurrence ----------------
__global__ __launch_bounds__(256)
__attribute__((amdgpu_waves_per_eu(4, 4)))
void snn_lif_kernel(const float* __restrict__ h1ws, // [4096,512]
                    const float* __restrict__ W2,   // [2,512]
                    const float* __restrict__ b2,   // [2]
                    const int* __restrict__ tsp,    // [1]
                    float* __restrict__ out)        // [4096,2]
{
    const int tid = threadIdx.x;
    const int l   = tid & 63;
    const int wid = tid >> 6;                 // 0..3
    const int row = blockIdx.x * 4 + wid;

    float hv[8], w0r[8], w1r[8], mem[8];
    #pragma unroll
    for (int j = 0; j < 8; ++j) {
        const int h = l + j * 64;             // consecutive lanes -> coalesced
        hv[j]  = h1ws[(size_t)row * 512 + h];
        w0r[j] = W2[h];
        w1r[j] = W2[512 + h];
        mem[j] = 0.0f;
    }
    const float bb0 = b2[0], bb1 = b2[1];
    const int   T   = tsp[0];

    float c0 = 0.0f, c1 = 0.0f;
    for (int t = 0; t < T; ++t) {
        float a0 = 0.0f, a1 = 0.0f, a0b = 0.0f, a1b = 0.0f;
        #pragma unroll
        for (int j = 0; j < 8; j += 2) {
            // membrane update non-fused to match reference algebra exactly
            float m0 = __fadd_rn(__fmul_rn(0.9f, mem[j]),     hv[j]);
            float m1 = __fadd_rn(__fmul_rn(0.9f, mem[j + 1]), hv[j + 1]);
            float s0 = (m0 > 1.0f) ? 1.0f : 0.0f;
            float s1 = (m1 > 1.0f) ? 1.0f : 0.0f;
            mem[j]     = m0 - s0;
            mem[j + 1] = m1 - s1;
            a0  = fmaf(s0, w0r[j],     a0);
            a1  = fmaf(s0, w1r[j],     a1);
            a0b = fmaf(s1, w0r[j + 1], a0b);
            a1b = fmaf(s1, w1r[j + 1], a1b);
        }
        a0 += a0b; a1 += a1b;
        // 64-lane reduce, pure VALU DPP (HW-verified R3-R5):
        a0 = dpp_add<0x121>(a0); a1 = dpp_add<0x121>(a1);  // row_ror 1
        a0 = dpp_add<0x122>(a0); a1 = dpp_add<0x122>(a1);  // row_ror 2
        a0 = dpp_add<0x124>(a0); a1 = dpp_add<0x124>(a1);  // row_ror 4
        a0 = dpp_add<0x128>(a0); a1 = dpp_add<0x128>(a1);  // row_ror 8
        a0 = dpp_add<0x142>(a0); a1 = dpp_add<0x142>(a1);  // row_bcast15
        a0 = dpp_add<0x143>(a0); a1 = dpp_add<0x143>(a1);  // row_bcast31
        // lanes 48..63 hold the full 512-sum
        c0 += ((a0 + bb0) > 0.0f) ? 1.0f : 0.0f;
        c1 += ((a1 + bb1) > 0.0f) ? 1.0f : 0.0f;
    }

    if (l == 48) {
        const float ft = (float)T;
        float2* dst = (float2*)(out + (size_t)row * 2);
        *dst = make_float2(c0 / ft, c1 / ft);
    }
}

// ---------------- Fallback: proven R1 fused kernel ----------------
#define BM 16
#define LDS_H_STRIDE 520

__global__ __launch_bounds__(256, 1) void snn_fused_kernel(
    const float* __restrict__ x, const float* __restrict__ W1,
    const float* __restrict__ b1, const float* __restrict__ W2,
    const float* __restrict__ b2, const int* __restrict__ tsp,
    float* __restrict__ out)
{
    __shared__ float xs[BM * 256];
    __shared__ float h1s[BM * LDS_H_STRIDE];

    const int tid  = threadIdx.x;
    const int row0 = blockIdx.x * BM;

    {
        const float4* xg  = (const float4*)(x + (size_t)row0 * 256);
        float4*       xsv = (float4*)xs;
        #pragma unroll
        for (int i = 0; i < 4; ++i)
            xsv[i * 256 + tid] = xg[i * 256 + tid];
    }
    __syncthreads();

    {
        const int h0 = tid * 2;
        float acc0[BM], acc1[BM];
        const float bia0 = b1[h0], bia1 = b1[h0 + 1];
        #pragma unroll
        for (int b = 0; b < BM; ++b) { acc0[b] = bia0; acc1[b] = bia1; }
        const float4* w0v = (const float4*)(W1 + (size_t)h0 * 256);
        const float4* w1v = (const float4*)(W1 + (size_t)(h0 + 1) * 256);
        const float4* xsv = (const float4*)xs;
        float4 wa = w0v[0], wb = w1v[0];
        #pragma unroll 1
        for (int k4 = 0; k4 < 64; ++k4) {
            const int kn = (k4 < 63) ? k4 + 1 : 63;
            float4 wan = w0v[kn], wbn = w1v[kn];
            float4 xv[BM];
            #pragma unroll
            for (int b = 0; b < BM; ++b) xv[b] = xsv[b * 64 + k4];
            #pragma unroll
            for (int b = 0; b < BM; ++b) {
                acc0[b] = fmaf(xv[b].x, wa.x, acc0[b]);
                acc0[b] = fmaf(xv[b].y, wa.y, acc0[b]);
                acc0[b] = fmaf(xv[b].z, wa.z, acc0[b]);
                acc0[b] = fmaf(xv[b].w, wa.w, acc0[b]);
                acc1[b] = fmaf(xv[b].x, wb.x, acc1[b]);
                acc1[b] = fmaf(xv[b].y, wb.y, acc1[b]);
                acc1[b] = fmaf(xv[b].z, wb.z, acc1[b]);
                acc1[b] = fmaf(xv[b].w, wb.w, acc1[b]);
            }
            wa = wan; wb = wbn;
        }
        #pragma unroll
        for (int b = 0; b < BM; ++b) {
            float2* dst = (float2*)&h1s[b * LDS_H_STRIDE + h0];
            *dst = make_float2(acc0[b], acc1[b]);
        }
    }
    __syncthreads();

    {
        const int l   = tid & 63;
        const int w   = tid >> 6;
        const int l15 = l & 15;
        const int b_local = w * 4 + (l >> 4);
        const int row = row0 + b_local;

        float hv[32], w0r[32], w1r[32], mem[32];
        #pragma unroll
        for (int j = 0; j < 32; ++j) {
            const int h = l15 + j * 16;
            hv[j]  = h1s[b_local * LDS_H_STRIDE + h];
            w0r[j] = W2[h];
            w1r[j] = W2[512 + h];
            mem[j] = 0.0f;
        }
        const float bb0 = b2[0], bb1 = b2[1];
        const int   T   = tsp[0];

        float c0 = 0.0f, c1 = 0.0f;
        for (int t = 0; t < T; ++t) {
            float a0 = 0.0f, a1 = 0.0f, a0b = 0.0f, a1b = 0.0f;
            #pragma unroll
            for (int j = 0; j < 32; j += 2) {
                float m0 = __fadd_rn(__fmul_rn(0.9f, mem[j]),     hv[j]);
                float m1 = __fadd_rn(__fmul_rn(0.9f, mem[j + 1]), hv[j + 1]);
                float s0 = (m0 > 1.0f) ? 1.0f : 0.0f;
                float s1 = (m1 > 1.0f) ? 1.0f : 0.0f;
                mem[j]     = m0 - s0;
                mem[j + 1] = m1 - s1;
                a0  = fmaf(s0, w0r[j],     a0);
                a1  = fmaf(s0, w1r[j],     a1);
                a0b = fmaf(s1, w0r[j + 1], a0b);
                a1b = fmaf(s1, w1r[j + 1], a1b);
            }
            a0 += a0b; a1 += a1b;
            a0 = dpp_add<0x121>(a0); a1 = dpp_add<0x121>(a1);
            a0 = dpp_add<0x122>(a0); a1 = dpp_add<0x122>(a1);
            a0 = dpp_add<0x124>(a0); a1 = dpp_add<0x124>(a1);
            a0 = dpp_add<0x128>(a0); a1 = dpp_add<0x128>(a1);
            c0 += ((a0 + bb0) > 0.0f) ? 1.0f : 0.0f;
            c1 += ((a1 + bb1) > 0.0f) ? 1.0f : 0.0f;
        }

        if (l15 == 0) {
            const float ft = (float)T;
            float2* dst = (float2*)(out + (size_t)row * 2);
            *dst = make_float2(c0 / ft, c1 / ft);
        }
    }
}

extern "C" void kernel_launch(void* const* d_in, const int* in_sizes, int n_in,
                              void* d_out, int out_size, void* d_ws, size_t ws_size,
                              hipStream_t stream) {
    const float* x   = (const float*)d_in[0];
    const float* W1  = (const float*)d_in[1];
    const float* b1  = (const float*)d_in[2];
    const float* W2  = (const float*)d_in[3];
    const float* b2  = (const float*)d_in[4];
    const int*   tsp = (const int*)d_in[5];
    float*       out = (float*)d_out;

    const int B = in_sizes[0] / 256;                     // 4096
    const size_t need = (size_t)B * 512 * sizeof(float); // 8 MiB

    if (ws_size >= need) {
        float* h1ws = (float*)d_ws;
        snn_fc1_kernel<<<dim3(B / AM, 512 / AN), dim3(256), 0, stream>>>(
            x, W1, b1, h1ws);
        snn_lif_kernel<<<dim3(B / 4), dim3(256), 0, stream>>>(
            h1ws, W2, b2, tsp, out);
    } else {
        snn_fused_kernel<<<dim3(B / BM), dim3(256), 0, stream>>>(
            x, W1, b1, W2, b2, tsp, out);
    }
}

// Round 7
// 76.322 us; speedup vs baseline: 1.9470x; 1.5405x over previous
//
#include <hip/hip_runtime.h>

// SNN binary classifier, two-kernel split. B=4096, D=256, H=512, O=2, T=100.
//
// R6 attribution: fc1=67us (VALUBusy 22%, latency-bound on per-thread W1
// global loads w/ 1-deep prefetch), LIF ~45us. R7 rewrites fc1 as an
// LDS-tiled fp32 GEMM: 64x64 tile, K in 4 chunks of 64, both operands
// staged in LDS, inner loop = broadcast ds_read_b128 + FMA only.
//   - x tile  : xs4[row][q] float4, row stride 17 float4 (68 dw) ->
//               4-unique-addr reads land on 2 banks x2 = 2-way = free.
//   - W1 tile : wsf[k][c] k-major, row stride 68 dw (16B-aligned) ->
//               per-k4 col vector is one contiguous b128; 16 unique addrs
//               over 8 banks = 2-way = free. Staged via coalesced float4
//               global reads (16 lanes = 256B contiguous per W1 row).
// Per-(row,col) FMA order: bias first, k ascending, float4 lanes x,y,z,w —
// bit-identical h1 to all passing rounds.
// LIF kernel: byte-for-byte the R6 version (passed, ~45us) — next target.

template <int CTRL>
__device__ __forceinline__ float dpp_add(float v) {
    int x = __builtin_amdgcn_update_dpp(0, __builtin_bit_cast(int, v),
                                        CTRL, 0xF, 0xF, false);
    return v + __builtin_bit_cast(float, x);
}

// ---------------- Kernel A: fc1 GEMM (LDS-tiled) ----------------
#define TM 64
#define TN 64
#define TK 64
#define XS_STRIDE4 17   // float4 units per x row (16 + 1 pad)
#define WS_STRIDE  68   // floats per k row (64 + 4 pad, 16B aligned)

__global__ __launch_bounds__(256)
__attribute__((amdgpu_waves_per_eu(2, 4)))
void snn_fc1_kernel(const float* __restrict__ x,   // [4096,256]
                    const float* __restrict__ W1,  // [512,256]
                    const float* __restrict__ b1,  // [512]
                    float* __restrict__ h1ws)      // [4096,512]
{
    __shared__ float4 xs4[TM * XS_STRIDE4];   // 17.0 KiB
    __shared__ float  wsf[TK * WS_STRIDE];    // 17.0 KiB

    const int tid  = threadIdx.x;
    const int row0 = blockIdx.x * TM;
    const int col0 = blockIdx.y * TN;

    const int tx = tid & 15;          // col group: cols col0 + tx*4 .. +3
    const int ty = tid >> 4;          // row group: rows row0 + ty*4 .. +3

    // bias init (bias first — matches reference accumulation order)
    float acc[4][4];
    {
        const float4 bv = ((const float4*)b1)[(col0 >> 2) + tx];
        #pragma unroll
        for (int r = 0; r < 4; ++r) {
            acc[r][0] = bv.x; acc[r][1] = bv.y;
            acc[r][2] = bv.z; acc[r][3] = bv.w;
        }
    }

    const float4* xg = (const float4*)x;   // [4096][64]
    const float4* wg = (const float4*)W1;  // [512][64]

    for (int chunk = 0; chunk < 4; ++chunk) {
        const int k0q = chunk * 16;        // k-chunk start in float4 units

        // ---- stage x chunk: 1024 float4, 4/thread, coalesced ----
        #pragma unroll
        for (int i = 0; i < 4; ++i) {
            const int idx = tid + i * 256;       // 0..1023
            const int row = idx >> 4;            // 0..63
            const int q   = idx & 15;            // 0..15
            xs4[row * XS_STRIDE4 + q] =
                xg[(size_t)(row0 + row) * 64 + k0q + q];
        }
        // ---- stage W1 chunk into k-major wsf[k][c] ----
        #pragma unroll
        for (int i = 0; i < 4; ++i) {
            const int idx = tid + i * 256;       // 0..1023
            const int q   = idx & 15;            // k4 within chunk
            const int c   = idx >> 4;            // 0..63
            const float4 wv4 = wg[(size_t)(col0 + c) * 64 + k0q + q];
            wsf[(q * 4 + 0) * WS_STRIDE + c] = wv4.x;
            wsf[(q * 4 + 1) * WS_STRIDE + c] = wv4.y;
            wsf[(q * 4 + 2) * WS_STRIDE + c] = wv4.z;
            wsf[(q * 4 + 3) * WS_STRIDE + c] = wv4.w;
        }
        __syncthreads();

        // ---- inner: 16 k4-steps, 8 b128 reads + 64 FMA each ----
        #pragma unroll
        for (int k4 = 0; k4 < 16; ++k4) {
            float4 xv[4], wv[4];
            #pragma unroll
            for (int r = 0; r < 4; ++r)
                xv[r] = xs4[(ty * 4 + r) * XS_STRIDE4 + k4];
            #pragma unroll
            for (int kk = 0; kk < 4; ++kk)
                wv[kk] = *(const float4*)&wsf[(k4 * 4 + kk) * WS_STRIDE + tx * 4];
            // k ascending per (r,c): kk outer-of-(r,c) loops
            #pragma unroll
            for (int kk = 0; kk < 4; ++kk) {
                const float xk0 = xv[0][kk], xk1 = xv[1][kk];
                const float xk2 = xv[2][kk], xk3 = xv[3][kk];
                #pragma unroll
                for (int cc = 0; cc < 4; ++cc) {
                    const float w = wv[kk][cc];
                    acc[0][cc] = fmaf(xk0, w, acc[0][cc]);
                    acc[1][cc] = fmaf(xk1, w, acc[1][cc]);
                    acc[2][cc] = fmaf(xk2, w, acc[2][cc]);
                    acc[3][cc] = fmaf(xk3, w, acc[3][cc]);
                }
            }
        }
        __syncthreads();
    }

    // ---- write 4 rows x 4 cols (float4 per row, coalesced) ----
    #pragma unroll
    for (int r = 0; r < 4; ++r) {
        float4* dst = (float4*)&h1ws[(size_t)(row0 + ty * 4 + r) * 512
                                     + col0 + tx * 4];
        *dst = make_float4(acc[r][0], acc[r][1], acc[r][2], acc[r][3]);
    }
}

// ---------------- Kernel B: LIF recurrence (byte-identical to R6) ----------------
__global__ __launch_bounds__(256)
__attribute__((amdgpu_waves_per_eu(4, 4)))
void snn_lif_kernel(const float* __restrict__ h1ws, // [4096,512]
                    const float* __restrict__ W2,   // [2,512]
                    const float* __restrict__ b2,   // [2]
                    const int* __restrict__ tsp,    // [1]
                    float* __restrict__ out)        // [4096,2]
{
    const int tid = threadIdx.x;
    const int l   = tid & 63;
    const int wid = tid >> 6;                 // 0..3
    const int row = blockIdx.x * 4 + wid;

    float hv[8], w0r[8], w1r[8], mem[8];
    #pragma unroll
    for (int j = 0; j < 8; ++j) {
        const int h = l + j * 64;             // consecutive lanes -> coalesced
        hv[j]  = h1ws[(size_t)row * 512 + h];
        w0r[j] = W2[h];
        w1r[j] = W2[512 + h];
        mem[j] = 0.0f;
    }
    const float bb0 = b2[0], bb1 = b2[1];
    const int   T   = tsp[0];

    float c0 = 0.0f, c1 = 0.0f;
    for (int t = 0; t < T; ++t) {
        float a0 = 0.0f, a1 = 0.0f, a0b = 0.0f, a1b = 0.0f;
        #pragma unroll
        for (int j = 0; j < 8; j += 2) {
            // membrane update non-fused to match reference algebra exactly
            float m0 = __fadd_rn(__fmul_rn(0.9f, mem[j]),     hv[j]);
            float m1 = __fadd_rn(__fmul_rn(0.9f, mem[j + 1]), hv[j + 1]);
            float s0 = (m0 > 1.0f) ? 1.0f : 0.0f;
            float s1 = (m1 > 1.0f) ? 1.0f : 0.0f;
            mem[j]     = m0 - s0;
            mem[j + 1] = m1 - s1;
            a0  = fmaf(s0, w0r[j],     a0);
            a1  = fmaf(s0, w1r[j],     a1);
            a0b = fmaf(s1, w0r[j + 1], a0b);
            a1b = fmaf(s1, w1r[j + 1], a1b);
        }
        a0 += a0b; a1 += a1b;
        // 64-lane reduce, pure VALU DPP (HW-verified R3-R6):
        a0 = dpp_add<0x121>(a0); a1 = dpp_add<0x121>(a1);  // row_ror 1
        a0 = dpp_add<0x122>(a0); a1 = dpp_add<0x122>(a1);  // row_ror 2
        a0 = dpp_add<0x124>(a0); a1 = dpp_add<0x124>(a1);  // row_ror 4
        a0 = dpp_add<0x128>(a0); a1 = dpp_add<0x128>(a1);  // row_ror 8
        a0 = dpp_add<0x142>(a0); a1 = dpp_add<0x142>(a1);  // row_bcast15
        a0 = dpp_add<0x143>(a0); a1 = dpp_add<0x143>(a1);  // row_bcast31
        // lanes 48..63 hold the full 512-sum
        c0 += ((a0 + bb0) > 0.0f) ? 1.0f : 0.0f;
        c1 += ((a1 + bb1) > 0.0f) ? 1.0f : 0.0f;
    }

    if (l == 48) {
        const float ft = (float)T;
        float2* dst = (float2*)(out + (size_t)row * 2);
        *dst = make_float2(c0 / ft, c1 / ft);
    }
}

// ---------------- Fallback: proven R1 fused kernel ----------------
#define BM 16
#define LDS_H_STRIDE 520

__global__ __launch_bounds__(256, 1) void snn_fused_kernel(
    const float* __restrict__ x, const float* __restrict__ W1,
    const float* __restrict__ b1, const float* __restrict__ W2,
    const float* __restrict__ b2, const int* __restrict__ tsp,
    float* __restrict__ out)
{
    __shared__ float xs[BM * 256];
    __shared__ float h1s[BM * LDS_H_STRIDE];

    const int tid  = threadIdx.x;
    const int row0 = blockIdx.x * BM;

    {
        const float4* xg  = (const float4*)(x + (size_t)row0 * 256);
        float4*       xsv = (float4*)xs;
        #pragma unroll
        for (int i = 0; i < 4; ++i)
            xsv[i * 256 + tid] = xg[i * 256 + tid];
    }
    __syncthreads();

    {
        const int h0 = tid * 2;
        float acc0[BM], acc1[BM];
        const float bia0 = b1[h0], bia1 = b1[h0 + 1];
        #pragma unroll
        for (int b = 0; b < BM; ++b) { acc0[b] = bia0; acc1[b] = bia1; }
        const float4* w0v = (const float4*)(W1 + (size_t)h0 * 256);
        const float4* w1v = (const float4*)(W1 + (size_t)(h0 + 1) * 256);
        const float4* xsv = (const float4*)xs;
        float4 wa = w0v[0], wb = w1v[0];
        #pragma unroll 1
        for (int k4 = 0; k4 < 64; ++k4) {
            const int kn = (k4 < 63) ? k4 + 1 : 63;
            float4 wan = w0v[kn], wbn = w1v[kn];
            float4 xv[BM];
            #pragma unroll
            for (int b = 0; b < BM; ++b) xv[b] = xsv[b * 64 + k4];
            #pragma unroll
            for (int b = 0; b < BM; ++b) {
                acc0[b] = fmaf(xv[b].x, wa.x, acc0[b]);
                acc0[b] = fmaf(xv[b].y, wa.y, acc0[b]);
                acc0[b] = fmaf(xv[b].z, wa.z, acc0[b]);
                acc0[b] = fmaf(xv[b].w, wa.w, acc0[b]);
                acc1[b] = fmaf(xv[b].x, wb.x, acc1[b]);
                acc1[b] = fmaf(xv[b].y, wb.y, acc1[b]);
                acc1[b] = fmaf(xv[b].z, wb.z, acc1[b]);
                acc1[b] = fmaf(xv[b].w, wb.w, acc1[b]);
            }
            wa = wan; wb = wbn;
        }
        #pragma unroll
        for (int b = 0; b < BM; ++b) {
            float2* dst = (float2*)&h1s[b * LDS_H_STRIDE + h0];
            *dst = make_float2(acc0[b], acc1[b]);
        }
    }
    __syncthreads();

    {
        const int l   = tid & 63;
        const int w   = tid >> 6;
        const int l15 = l & 15;
        const int b_local = w * 4 + (l >> 4);
        const int row = row0 + b_local;

        float hv[32], w0r[32], w1r[32], mem[32];
        #pragma unroll
        for (int j = 0; j < 32; ++j) {
            const int h = l15 + j * 16;
            hv[j]  = h1s[b_local * LDS_H_STRIDE + h];
            w0r[j] = W2[h];
            w1r[j] = W2[512 + h];
            mem[j] = 0.0f;
        }
        const float bb0 = b2[0], bb1 = b2[1];
        const int   T   = tsp[0];

        float c0 = 0.0f, c1 = 0.0f;
        for (int t = 0; t < T; ++t) {
            float a0 = 0.0f, a1 = 0.0f, a0b = 0.0f, a1b = 0.0f;
            #pragma unroll
            for (int j = 0; j < 32; j += 2) {
                float m0 = __fadd_rn(__fmul_rn(0.9f, mem[j]),     hv[j]);
                float m1 = __fadd_rn(__fmul_rn(0.9f, mem[j + 1]), hv[j + 1]);
                float s0 = (m0 > 1.0f) ? 1.0f : 0.0f;
                float s1 = (m1 > 1.0f) ? 1.0f : 0.0f;
                mem[j]     = m0 - s0;
                mem[j + 1] = m1 - s1;
                a0  = fmaf(s0, w0r[j],     a0);
                a1  = fmaf(s0, w1r[j],     a1);
                a0b = fmaf(s1, w0r[j + 1], a0b);
                a1b = fmaf(s1, w1r[j + 1], a1b);
            }
            a0 += a0b; a1 += a1b;
            a0 = dpp_add<0x121>(a0); a1 = dpp_add<0x121>(a1);
            a0 = dpp_add<0x122>(a0); a1 = dpp_add<0x122>(a1);
            a0 = dpp_add<0x124>(a0); a1 = dpp_add<0x124>(a1);
            a0 = dpp_add<0x128>(a0); a1 = dpp_add<0x128>(a1);
            c0 += ((a0 + bb0) > 0.0f) ? 1.0f : 0.0f;
            c1 += ((a1 + bb1) > 0.0f) ? 1.0f : 0.0f;
        }

        if (l15 == 0) {
            const float ft = (float)T;
            float2* dst = (float2*)(out + (size_t)row * 2);
            *dst = make_float2(c0 / ft, c1 / ft);
        }
    }
}

extern "C" void kernel_launch(void* const* d_in, const int* in_sizes, int n_in,
                              void* d_out, int out_size, void* d_ws, size_t ws_size,
                              hipStream_t stream) {
    const float* x   = (const float*)d_in[0];
    const float* W1  = (const float*)d_in[1];
    const float* b1  = (const float*)d_in[2];
    const float* W2  = (const float*)d_in[3];
    const float* b2  = (const float*)d_in[4];
    const int*   tsp = (const int*)d_in[5];
    float*       out = (float*)d_out;

    const int B = in_sizes[0] / 256;                     // 4096
    const size_t need = (size_t)B * 512 * sizeof(float); // 8 MiB

    if (ws_size >= need) {
        float* h1ws = (float*)d_ws;
        snn_fc1_kernel<<<dim3(B / TM, 512 / TN), dim3(256), 0, stream>>>(
            x, W1, b1, h1ws);
        snn_lif_kernel<<<dim3(B / 4), dim3(256), 0, stream>>>(
            h1ws, W2, b2, tsp, out);
    } else {
        snn_fused_kernel<<<dim3(B / BM), dim3(256), 0, stream>>>(
            x, W1, b1, W2, b2, tsp, out);
    }
}

// Round 8
// 69.512 us; speedup vs baseline: 2.1378x; 1.0980x over previous
//
#include <hip/hip_runtime.h>

// SNN binary classifier, two-kernel split. B=4096, D=256, H=512, O=2, T=100.
//
// R7 attribution: LIF=60us issue-bound (~110 VALU instr/step), fc1=15us.
// R8: dead-element compaction. LIF recurrence mem_{t+1}=0.9*mem_t+h1 with
// mem_0=0 is monotone toward 10*h1; max over 100 steps = 9.99973*h1, fp32
// rounding drift <= 1.2e-6 (0.9-contraction). So h1 <= 0.0999 (< bound
// 0.0999975) can NEVER spike -> contributes exactly +0.0 to every h2 sum.
// ~54% of elements are dead; drop them. Live trajectories stay bit-identical;
// only the h2 summation order changes (~1e-7, already different from numpy's
// order since R1 and tolerated).
//   LIF prologue (per wave): ballot+popcll compaction of live (h1,idx) into
//   LDS; gather W2 by idx once; t-loop runs ceil(live/64) chunks via
//   wave-uniform switch into 8 static template bodies (no runtime reg idx).
//   Zero-filled slots: mem stays 0 -> s=0 -> exact +0.0, harmless.
// fc1: byte-identical to R7 (h1 bit-identical to all passing rounds).

template <int CTRL>
__device__ __forceinline__ float dpp_add(float v) {
    int x = __builtin_amdgcn_update_dpp(0, __builtin_bit_cast(int, v),
                                        CTRL, 0xF, 0xF, false);
    return v + __builtin_bit_cast(float, x);
}

// ---------------- Kernel A: fc1 GEMM (LDS-tiled, byte-identical to R7) ----------------
#define TM 64
#define TN 64
#define TK 64
#define XS_STRIDE4 17   // float4 units per x row (16 + 1 pad)
#define WS_STRIDE  68   // floats per k row (64 + 4 pad, 16B aligned)

__global__ __launch_bounds__(256)
__attribute__((amdgpu_waves_per_eu(2, 4)))
void snn_fc1_kernel(const float* __restrict__ x,   // [4096,256]
                    const float* __restrict__ W1,  // [512,256]
                    const float* __restrict__ b1,  // [512]
                    float* __restrict__ h1ws)      // [4096,512]
{
    __shared__ float4 xs4[TM * XS_STRIDE4];   // 17.0 KiB
    __shared__ float  wsf[TK * WS_STRIDE];    // 17.0 KiB

    const int tid  = threadIdx.x;
    const int row0 = blockIdx.x * TM;
    const int col0 = blockIdx.y * TN;

    const int tx = tid & 15;
    const int ty = tid >> 4;

    float acc[4][4];
    {
        const float4 bv = ((const float4*)b1)[(col0 >> 2) + tx];
        #pragma unroll
        for (int r = 0; r < 4; ++r) {
            acc[r][0] = bv.x; acc[r][1] = bv.y;
            acc[r][2] = bv.z; acc[r][3] = bv.w;
        }
    }

    const float4* xg = (const float4*)x;   // [4096][64]
    const float4* wg = (const float4*)W1;  // [512][64]

    for (int chunk = 0; chunk < 4; ++chunk) {
        const int k0q = chunk * 16;

        #pragma unroll
        for (int i = 0; i < 4; ++i) {
            const int idx = tid + i * 256;
            const int row = idx >> 4;
            const int q   = idx & 15;
            xs4[row * XS_STRIDE4 + q] =
                xg[(size_t)(row0 + row) * 64 + k0q + q];
        }
        #pragma unroll
        for (int i = 0; i < 4; ++i) {
            const int idx = tid + i * 256;
            const int q   = idx & 15;
            const int c   = idx >> 4;
            const float4 wv4 = wg[(size_t)(col0 + c) * 64 + k0q + q];
            wsf[(q * 4 + 0) * WS_STRIDE + c] = wv4.x;
            wsf[(q * 4 + 1) * WS_STRIDE + c] = wv4.y;
            wsf[(q * 4 + 2) * WS_STRIDE + c] = wv4.z;
            wsf[(q * 4 + 3) * WS_STRIDE + c] = wv4.w;
        }
        __syncthreads();

        #pragma unroll
        for (int k4 = 0; k4 < 16; ++k4) {
            float4 xv[4], wv[4];
            #pragma unroll
            for (int r = 0; r < 4; ++r)
                xv[r] = xs4[(ty * 4 + r) * XS_STRIDE4 + k4];
            #pragma unroll
            for (int kk = 0; kk < 4; ++kk)
                wv[kk] = *(const float4*)&wsf[(k4 * 4 + kk) * WS_STRIDE + tx * 4];
            #pragma unroll
            for (int kk = 0; kk < 4; ++kk) {
                const float xk0 = xv[0][kk], xk1 = xv[1][kk];
                const float xk2 = xv[2][kk], xk3 = xv[3][kk];
                #pragma unroll
                for (int cc = 0; cc < 4; ++cc) {
                    const float w = wv[kk][cc];
                    acc[0][cc] = fmaf(xk0, w, acc[0][cc]);
                    acc[1][cc] = fmaf(xk1, w, acc[1][cc]);
                    acc[2][cc] = fmaf(xk2, w, acc[2][cc]);
                    acc[3][cc] = fmaf(xk3, w, acc[3][cc]);
                }
            }
        }
        __syncthreads();
    }

    #pragma unroll
    for (int r = 0; r < 4; ++r) {
        float4* dst = (float4*)&h1ws[(size_t)(row0 + ty * 4 + r) * 512
                                     + col0 + tx * 4];
        *dst = make_float4(acc[r][0], acc[r][1], acc[r][2], acc[r][3]);
    }
}

// ---------------- Kernel B: LIF with dead-element compaction ----------------
#define DEAD_CUT 0.0999f   // provably-never-spikes bound is 0.0999975

template <int E>
__device__ __forceinline__ void lif_body(const float2* __restrict__ cl, int l,
                                         const float* __restrict__ W2,
                                         float bb0, float bb1, int T,
                                         float* __restrict__ dst)
{
    float hv[E], w0r[E], w1r[E], mem[E];
    #pragma unroll
    for (int j = 0; j < E; ++j) {
        const float2 p = cl[j * 64 + l];
        hv[j] = p.x;
        const int idx = __float_as_int(p.y);
        w0r[j] = W2[idx];
        w1r[j] = W2[512 + idx];
        mem[j] = 0.0f;
    }
    float c0 = 0.0f, c1 = 0.0f;
    for (int t = 0; t < T; ++t) {
        float a0 = 0.0f, a1 = 0.0f, a0b = 0.0f, a1b = 0.0f;
        #pragma unroll
        for (int j = 0; j < E; ++j) {
            // membrane update non-fused to match reference algebra exactly
            const float m = __fadd_rn(__fmul_rn(0.9f, mem[j]), hv[j]);
            const float s = (m > 1.0f) ? 1.0f : 0.0f;
            mem[j] = m - s;
            if ((j & 1) == 0) { a0  = fmaf(s, w0r[j], a0);  a1  = fmaf(s, w1r[j], a1);  }
            else              { a0b = fmaf(s, w0r[j], a0b); a1b = fmaf(s, w1r[j], a1b); }
        }
        a0 += a0b; a1 += a1b;
        // 64-lane reduce, pure VALU DPP (HW-verified R3-R7):
        a0 = dpp_add<0x121>(a0); a1 = dpp_add<0x121>(a1);  // row_ror 1
        a0 = dpp_add<0x122>(a0); a1 = dpp_add<0x122>(a1);  // row_ror 2
        a0 = dpp_add<0x124>(a0); a1 = dpp_add<0x124>(a1);  // row_ror 4
        a0 = dpp_add<0x128>(a0); a1 = dpp_add<0x128>(a1);  // row_ror 8
        a0 = dpp_add<0x142>(a0); a1 = dpp_add<0x142>(a1);  // row_bcast15
        a0 = dpp_add<0x143>(a0); a1 = dpp_add<0x143>(a1);  // row_bcast31
        c0 += ((a0 + bb0) > 0.0f) ? 1.0f : 0.0f;
        c1 += ((a1 + bb1) > 0.0f) ? 1.0f : 0.0f;
    }
    if (l == 48) {
        const float ft = (float)T;
        *(float2*)dst = make_float2(c0 / ft, c1 / ft);
    }
}

__global__ __launch_bounds__(256)
__attribute__((amdgpu_waves_per_eu(4, 4)))
void snn_lif_kernel(const float* __restrict__ h1ws, // [4096,512]
                    const float* __restrict__ W2,   // [2,512]
                    const float* __restrict__ b2,   // [2]
                    const int* __restrict__ tsp,    // [1]
                    float* __restrict__ out)        // [4096,2]
{
    __shared__ float2 comp[4][512];   // 16 KiB: per-wave compacted (h1, idx)

    const int tid = threadIdx.x;
    const int l   = tid & 63;
    const int wid = tid >> 6;
    const int row = blockIdx.x * 4 + wid;

    // zero-fill (slots >= count must be exact-0 drive -> never spike)
    #pragma unroll
    for (int j = 0; j < 8; ++j)
        comp[wid][j * 64 + l] = make_float2(0.0f, __int_as_float(0));

    // ballot/popcount stream compaction of live elements (h1 > DEAD_CUT)
    const float* hrow = h1ws + (size_t)row * 512;
    unsigned base = 0;
    #pragma unroll
    for (int j = 0; j < 8; ++j) {
        const int h = j * 64 + l;
        const float v = hrow[h];
        const bool live = v > DEAD_CUT;
        const unsigned long long m = __ballot(live);
        const unsigned pos = (unsigned)__popcll(m & ((1ull << l) - 1ull));
        if (live) comp[wid][base + pos] = make_float2(v, __int_as_float(h));
        base += (unsigned)__popcll(m);
    }
    __syncthreads();

    const float bb0 = b2[0], bb1 = b2[1];
    const int   T   = tsp[0];
    float* dst = out + (size_t)row * 2;

    int trips = (int)((base + 63u) >> 6);
    if (trips < 1) trips = 1;
    const float2* cl = comp[wid];

    switch (trips) {
        case 1: lif_body<1>(cl, l, W2, bb0, bb1, T, dst); break;
        case 2: lif_body<2>(cl, l, W2, bb0, bb1, T, dst); break;
        case 3: lif_body<3>(cl, l, W2, bb0, bb1, T, dst); break;
        case 4: lif_body<4>(cl, l, W2, bb0, bb1, T, dst); break;
        case 5: lif_body<5>(cl, l, W2, bb0, bb1, T, dst); break;
        case 6: lif_body<6>(cl, l, W2, bb0, bb1, T, dst); break;
        case 7: lif_body<7>(cl, l, W2, bb0, bb1, T, dst); break;
        default: lif_body<8>(cl, l, W2, bb0, bb1, T, dst); break;
    }
}

// ---------------- Fallback: proven R1 fused kernel ----------------
#define BM 16
#define LDS_H_STRIDE 520

__global__ __launch_bounds__(256, 1) void snn_fused_kernel(
    const float* __restrict__ x, const float* __restrict__ W1,
    const float* __restrict__ b1, const float* __restrict__ W2,
    const float* __restrict__ b2, const int* __restrict__ tsp,
    float* __restrict__ out)
{
    __shared__ float xs[BM * 256];
    __shared__ float h1s[BM * LDS_H_STRIDE];

    const int tid  = threadIdx.x;
    const int row0 = blockIdx.x * BM;

    {
        const float4* xg  = (const float4*)(x + (size_t)row0 * 256);
        float4*       xsv = (float4*)xs;
        #pragma unroll
        for (int i = 0; i < 4; ++i)
            xsv[i * 256 + tid] = xg[i * 256 + tid];
    }
    __syncthreads();

    {
        const int h0 = tid * 2;
        float acc0[BM], acc1[BM];
        const float bia0 = b1[h0], bia1 = b1[h0 + 1];
        #pragma unroll
        for (int b = 0; b < BM; ++b) { acc0[b] = bia0; acc1[b] = bia1; }
        const float4* w0v = (const float4*)(W1 + (size_t)h0 * 256);
        const float4* w1v = (const float4*)(W1 + (size_t)(h0 + 1) * 256);
        const float4* xsv = (const float4*)xs;
        float4 wa = w0v[0], wb = w1v[0];
        #pragma unroll 1
        for (int k4 = 0; k4 < 64; ++k4) {
            const int kn = (k4 < 63) ? k4 + 1 : 63;
            float4 wan = w0v[kn], wbn = w1v[kn];
            float4 xv[BM];
            #pragma unroll
            for (int b = 0; b < BM; ++b) xv[b] = xsv[b * 64 + k4];
            #pragma unroll
            for (int b = 0; b < BM; ++b) {
                acc0[b] = fmaf(xv[b].x, wa.x, acc0[b]);
                acc0[b] = fmaf(xv[b].y, wa.y, acc0[b]);
                acc0[b] = fmaf(xv[b].z, wa.z, acc0[b]);
                acc0[b] = fmaf(xv[b].w, wa.w, acc0[b]);
                acc1[b] = fmaf(xv[b].x, wb.x, acc1[b]);
                acc1[b] = fmaf(xv[b].y, wb.y, acc1[b]);
                acc1[b] = fmaf(xv[b].z, wb.z, acc1[b]);
                acc1[b] = fmaf(xv[b].w, wb.w, acc1[b]);
            }
            wa = wan; wb = wbn;
        }
        #pragma unroll
        for (int b = 0; b < BM; ++b) {
            float2* dst = (float2*)&h1s[b * LDS_H_STRIDE + h0];
            *dst = make_float2(acc0[b], acc1[b]);
        }
    }
    __syncthreads();

    {
        const int l   = tid & 63;
        const int w   = tid >> 6;
        const int l15 = l & 15;
        const int b_local = w * 4 + (l >> 4);
        const int row = row0 + b_local;

        float hv[32], w0r[32], w1r[32], mem[32];
        #pragma unroll
        for (int j = 0; j < 32; ++j) {
            const int h = l15 + j * 16;
            hv[j]  = h1s[b_local * LDS_H_STRIDE + h];
            w0r[j] = W2[h];
            w1r[j] = W2[512 + h];
            mem[j] = 0.0f;
        }
        const float bb0 = b2[0], bb1 = b2[1];
        const int   T   = tsp[0];

        float c0 = 0.0f, c1 = 0.0f;
        for (int t = 0; t < T; ++t) {
            float a0 = 0.0f, a1 = 0.0f, a0b = 0.0f, a1b = 0.0f;
            #pragma unroll
            for (int j = 0; j < 32; j += 2) {
                float m0 = __fadd_rn(__fmul_rn(0.9f, mem[j]),     hv[j]);
                float m1 = __fadd_rn(__fmul_rn(0.9f, mem[j + 1]), hv[j + 1]);
                float s0 = (m0 > 1.0f) ? 1.0f : 0.0f;
                float s1 = (m1 > 1.0f) ? 1.0f : 0.0f;
                mem[j]     = m0 - s0;
                mem[j + 1] = m1 - s1;
                a0  = fmaf(s0, w0r[j],     a0);
                a1  = fmaf(s0, w1r[j],     a1);
                a0b = fmaf(s1, w0r[j + 1], a0b);
                a1b = fmaf(s1, w1r[j + 1], a1b);
            }
            a0 += a0b; a1 += a1b;
            a0 = dpp_add<0x121>(a0); a1 = dpp_add<0x121>(a1);
            a0 = dpp_add<0x122>(a0); a1 = dpp_add<0x122>(a1);
            a0 = dpp_add<0x124>(a0); a1 = dpp_add<0x124>(a1);
            a0 = dpp_add<0x128>(a0); a1 = dpp_add<0x128>(a1);
            c0 += ((a0 + bb0) > 0.0f) ? 1.0f : 0.0f;
            c1 += ((a1 + bb1) > 0.0f) ? 1.0f : 0.0f;
        }

        if (l15 == 0) {
            const float ft = (float)T;
            float2* dst = (float2*)(out + (size_t)row * 2);
            *dst = make_float2(c0 / ft, c1 / ft);
        }
    }
}

extern "C" void kernel_launch(void* const* d_in, const int* in_sizes, int n_in,
                              void* d_out, int out_size, void* d_ws, size_t ws_size,
                              hipStream_t stream) {
    const float* x   = (const float*)d_in[0];
    const float* W1  = (const float*)d_in[1];
    const float* b1  = (const float*)d_in[2];
    const float* W2  = (const float*)d_in[3];
    const float* b2  = (const float*)d_in[4];
    const int*   tsp = (const int*)d_in[5];
    float*       out = (float*)d_out;

    const int B = in_sizes[0] / 256;                     // 4096
    const size_t need = (size_t)B * 512 * sizeof(float); // 8 MiB

    if (ws_size >= need) {
        float* h1ws = (float*)d_ws;
        snn_fc1_kernel<<<dim3(B / TM, 512 / TN), dim3(256), 0, stream>>>(
            x, W1, b1, h1ws);
        snn_lif_kernel<<<dim3(B / 4), dim3(256), 0, stream>>>(
            h1ws, W2, b2, tsp, out);
    } else {
        snn_fused_kernel<<<dim3(B / BM), dim3(256), 0, stream>>>(
            x, W1, b1, W2, b2, tsp, out);
    }
}

// Round 9
// 58.365 us; speedup vs baseline: 2.5460x; 1.1910x over previous
//
#include <hip/hip_runtime.h>

// SNN binary classifier, two-kernel split. B=4096, D=256, H=512, O=2, T=100.
//
// R8 post-mortem: LIF fixed per-step cost (12-stage DPP reduce + hazards)
// ~= 41us of 50us; element work is minor after compaction. R9: amortize the
// reduce across rows — 2 batch rows per wave (32 lanes each). ror1/2/4/8
// gives each 16-lane row its partial; row_bcast15 completes: lanes 16-31
// hold row A's 512-sum, lanes 48-63 row B's (lane47->row3 cross-term only
// pollutes unused lanes 32-47; semantics HW-verified by the R1-R8 6-stage
// reduce). 5 DPP stages serve 2 rows: per-row reduce 12 -> 5 dpp_adds.
// Compaction (h1 > DEAD_CUT can never spike, proof in R8 header) unchanged,
// run once per row; comp LDS is wave-private -> no barrier.
// fc1: byte-identical to R7/R8 (h1 bit-identical to all passing rounds).

template <int CTRL>
__device__ __forceinline__ float dpp_add(float v) {
    int x = __builtin_amdgcn_update_dpp(0, __builtin_bit_cast(int, v),
                                        CTRL, 0xF, 0xF, false);
    return v + __builtin_bit_cast(float, x);
}

// ---------------- Kernel A: fc1 GEMM (LDS-tiled, byte-identical to R7) ----------------
#define TM 64
#define TN 64
#define TK 64
#define XS_STRIDE4 17   // float4 units per x row (16 + 1 pad)
#define WS_STRIDE  68   // floats per k row (64 + 4 pad, 16B aligned)

__global__ __launch_bounds__(256)
__attribute__((amdgpu_waves_per_eu(2, 4)))
void snn_fc1_kernel(const float* __restrict__ x,   // [4096,256]
                    const float* __restrict__ W1,  // [512,256]
                    const float* __restrict__ b1,  // [512]
                    float* __restrict__ h1ws)      // [4096,512]
{
    __shared__ float4 xs4[TM * XS_STRIDE4];   // 17.0 KiB
    __shared__ float  wsf[TK * WS_STRIDE];    // 17.0 KiB

    const int tid  = threadIdx.x;
    const int row0 = blockIdx.x * TM;
    const int col0 = blockIdx.y * TN;

    const int tx = tid & 15;
    const int ty = tid >> 4;

    float acc[4][4];
    {
        const float4 bv = ((const float4*)b1)[(col0 >> 2) + tx];
        #pragma unroll
        for (int r = 0; r < 4; ++r) {
            acc[r][0] = bv.x; acc[r][1] = bv.y;
            acc[r][2] = bv.z; acc[r][3] = bv.w;
        }
    }

    const float4* xg = (const float4*)x;   // [4096][64]
    const float4* wg = (const float4*)W1;  // [512][64]

    for (int chunk = 0; chunk < 4; ++chunk) {
        const int k0q = chunk * 16;

        #pragma unroll
        for (int i = 0; i < 4; ++i) {
            const int idx = tid + i * 256;
            const int row = idx >> 4;
            const int q   = idx & 15;
            xs4[row * XS_STRIDE4 + q] =
                xg[(size_t)(row0 + row) * 64 + k0q + q];
        }
        #pragma unroll
        for (int i = 0; i < 4; ++i) {
            const int idx = tid + i * 256;
            const int q   = idx & 15;
            const int c   = idx >> 4;
            const float4 wv4 = wg[(size_t)(col0 + c) * 64 + k0q + q];
            wsf[(q * 4 + 0) * WS_STRIDE + c] = wv4.x;
            wsf[(q * 4 + 1) * WS_STRIDE + c] = wv4.y;
            wsf[(q * 4 + 2) * WS_STRIDE + c] = wv4.z;
            wsf[(q * 4 + 3) * WS_STRIDE + c] = wv4.w;
        }
        __syncthreads();

        #pragma unroll
        for (int k4 = 0; k4 < 16; ++k4) {
            float4 xv[4], wv[4];
            #pragma unroll
            for (int r = 0; r < 4; ++r)
                xv[r] = xs4[(ty * 4 + r) * XS_STRIDE4 + k4];
            #pragma unroll
            for (int kk = 0; kk < 4; ++kk)
                wv[kk] = *(const float4*)&wsf[(k4 * 4 + kk) * WS_STRIDE + tx * 4];
            #pragma unroll
            for (int kk = 0; kk < 4; ++kk) {
                const float xk0 = xv[0][kk], xk1 = xv[1][kk];
                const float xk2 = xv[2][kk], xk3 = xv[3][kk];
                #pragma unroll
                for (int cc = 0; cc < 4; ++cc) {
                    const float w = wv[kk][cc];
                    acc[0][cc] = fmaf(xk0, w, acc[0][cc]);
                    acc[1][cc] = fmaf(xk1, w, acc[1][cc]);
                    acc[2][cc] = fmaf(xk2, w, acc[2][cc]);
                    acc[3][cc] = fmaf(xk3, w, acc[3][cc]);
                }
            }
        }
        __syncthreads();
    }

    #pragma unroll
    for (int r = 0; r < 4; ++r) {
        float4* dst = (float4*)&h1ws[(size_t)(row0 + ty * 4 + r) * 512
                                     + col0 + tx * 4];
        *dst = make_float4(acc[r][0], acc[r][1], acc[r][2], acc[r][3]);
    }
}

// ---------------- Kernel B: LIF, 2 rows/wave + compaction ----------------
#define DEAD_CUT 0.0999f   // provably-never-spikes bound is 0.0999975

template <int E>
__device__ __forceinline__ void lif_body2(const float2* __restrict__ cl, int l31,
                                          const float* __restrict__ W2,
                                          float bb0, float bb1, int T,
                                          float* __restrict__ dst, bool writer)
{
    float hv[E], w0r[E], w1r[E], mem[E];
    #pragma unroll
    for (int j = 0; j < E; ++j) {
        const float2 p = cl[j * 32 + l31];
        hv[j] = p.x;
        const int idx = __float_as_int(p.y);
        w0r[j] = W2[idx];
        w1r[j] = W2[512 + idx];
        mem[j] = 0.0f;
    }
    float c0 = 0.0f, c1 = 0.0f;
    for (int t = 0; t < T; ++t) {
        float a0 = 0.0f, a1 = 0.0f, a0b = 0.0f, a1b = 0.0f;
        #pragma unroll
        for (int j = 0; j < E; ++j) {
            // membrane update non-fused to match reference algebra exactly
            const float m = __fadd_rn(__fmul_rn(0.9f, mem[j]), hv[j]);
            const float s = (m > 1.0f) ? 1.0f : 0.0f;
            mem[j] = m - s;
            if ((j & 1) == 0) { a0  = fmaf(s, w0r[j], a0);  a1  = fmaf(s, w1r[j], a1);  }
            else              { a0b = fmaf(s, w0r[j], a0b); a1b = fmaf(s, w1r[j], a1b); }
        }
        a0 += a0b; a1 += a1b;
        // 5-stage reduce: 16-lane rows then bcast15 across each 32-half.
        // Lanes 16-31 -> row A full sum, lanes 48-63 -> row B full sum.
        a0 = dpp_add<0x121>(a0); a1 = dpp_add<0x121>(a1);  // row_ror 1
        a0 = dpp_add<0x122>(a0); a1 = dpp_add<0x122>(a1);  // row_ror 2
        a0 = dpp_add<0x124>(a0); a1 = dpp_add<0x124>(a1);  // row_ror 4
        a0 = dpp_add<0x128>(a0); a1 = dpp_add<0x128>(a1);  // row_ror 8
        a0 = dpp_add<0x142>(a0); a1 = dpp_add<0x142>(a1);  // row_bcast15
        c0 += ((a0 + bb0) > 0.0f) ? 1.0f : 0.0f;
        c1 += ((a1 + bb1) > 0.0f) ? 1.0f : 0.0f;
    }
    if (writer) {
        const float ft = (float)T;
        *(float2*)dst = make_float2(c0 / ft, c1 / ft);
    }
}

__global__ __launch_bounds__(256)
__attribute__((amdgpu_waves_per_eu(2, 4)))
void snn_lif_kernel(const float* __restrict__ h1ws, // [4096,512]
                    const float* __restrict__ W2,   // [2,512]
                    const float* __restrict__ b2,   // [2]
                    const int* __restrict__ tsp,    // [1]
                    float* __restrict__ out)        // [4096,2]
{
    __shared__ float2 comp[8][512];   // 32 KiB: per-row compacted (h1, idx)

    const int tid  = threadIdx.x;
    const int l    = tid & 63;
    const int wid  = tid >> 6;
    const int half = l >> 5;          // 0: row A, 1: row B
    const int l31  = l & 31;
    const int rowA = blockIdx.x * 8 + wid * 2;

    // per-row zero-fill + 64-lane ballot compaction (proven R8 code), x2 rows
    unsigned bases[2];
    #pragma unroll
    for (int r = 0; r < 2; ++r) {
        float2* cw = comp[wid * 2 + r];
        #pragma unroll
        for (int j = 0; j < 8; ++j)
            cw[j * 64 + l] = make_float2(0.0f, __int_as_float(0));
        const float* hrow = h1ws + (size_t)(rowA + r) * 512;
        unsigned base = 0;
        #pragma unroll
        for (int j = 0; j < 8; ++j) {
            const int h = j * 64 + l;
            const float v = hrow[h];
            const bool live = v > DEAD_CUT;
            const unsigned long long m = __ballot(live);
            const unsigned pos = (unsigned)__popcll(m & ((1ull << l) - 1ull));
            if (live) cw[base + pos] = make_float2(v, __int_as_float(h));
            base += (unsigned)__popcll(m);
        }
        bases[r] = base;
    }
    // comp is wave-private (same wave writes & reads) -> no __syncthreads

    const float bb0 = b2[0], bb1 = b2[1];
    const int   T   = tsp[0];
    const int   row = rowA + half;
    float* dst = out + (size_t)row * 2;
    const bool writer = (l31 == 16);      // lanes 16 (row A) and 48 (row B)

    const unsigned mx = bases[0] > bases[1] ? bases[0] : bases[1];
    int trips = (int)((mx + 31u) >> 5);
    if (trips < 1) trips = 1;
    const float2* cl = comp[wid * 2 + half];

    switch (trips) {
        case 1:  lif_body2<1>(cl, l31, W2, bb0, bb1, T, dst, writer); break;
        case 2:  lif_body2<2>(cl, l31, W2, bb0, bb1, T, dst, writer); break;
        case 3:  lif_body2<3>(cl, l31, W2, bb0, bb1, T, dst, writer); break;
        case 4:  lif_body2<4>(cl, l31, W2, bb0, bb1, T, dst, writer); break;
        case 5:  lif_body2<5>(cl, l31, W2, bb0, bb1, T, dst, writer); break;
        case 6:  lif_body2<6>(cl, l31, W2, bb0, bb1, T, dst, writer); break;
        case 7:  lif_body2<7>(cl, l31, W2, bb0, bb1, T, dst, writer); break;
        case 8:  lif_body2<8>(cl, l31, W2, bb0, bb1, T, dst, writer); break;
        case 9:  lif_body2<9>(cl, l31, W2, bb0, bb1, T, dst, writer); break;
        case 10: lif_body2<10>(cl, l31, W2, bb0, bb1, T, dst, writer); break;
        case 11: lif_body2<11>(cl, l31, W2, bb0, bb1, T, dst, writer); break;
        case 12: lif_body2<12>(cl, l31, W2, bb0, bb1, T, dst, writer); break;
        case 13: lif_body2<13>(cl, l31, W2, bb0, bb1, T, dst, writer); break;
        case 14: lif_body2<14>(cl, l31, W2, bb0, bb1, T, dst, writer); break;
        case 15: lif_body2<15>(cl, l31, W2, bb0, bb1, T, dst, writer); break;
        default: lif_body2<16>(cl, l31, W2, bb0, bb1, T, dst, writer); break;
    }
}

// ---------------- Fallback: proven R1 fused kernel ----------------
#define BM 16
#define LDS_H_STRIDE 520

__global__ __launch_bounds__(256, 1) void snn_fused_kernel(
    const float* __restrict__ x, const float* __restrict__ W1,
    const float* __restrict__ b1, const float* __restrict__ W2,
    const float* __restrict__ b2, const int* __restrict__ tsp,
    float* __restrict__ out)
{
    __shared__ float xs[BM * 256];
    __shared__ float h1s[BM * LDS_H_STRIDE];

    const int tid  = threadIdx.x;
    const int row0 = blockIdx.x * BM;

    {
        const float4* xg  = (const float4*)(x + (size_t)row0 * 256);
        float4*       xsv = (float4*)xs;
        #pragma unroll
        for (int i = 0; i < 4; ++i)
            xsv[i * 256 + tid] = xg[i * 256 + tid];
    }
    __syncthreads();

    {
        const int h0 = tid * 2;
        float acc0[BM], acc1[BM];
        const float bia0 = b1[h0], bia1 = b1[h0 + 1];
        #pragma unroll
        for (int b = 0; b < BM; ++b) { acc0[b] = bia0; acc1[b] = bia1; }
        const float4* w0v = (const float4*)(W1 + (size_t)h0 * 256);
        const float4* w1v = (const float4*)(W1 + (size_t)(h0 + 1) * 256);
        const float4* xsv = (const float4*)xs;
        float4 wa = w0v[0], wb = w1v[0];
        #pragma unroll 1
        for (int k4 = 0; k4 < 64; ++k4) {
            const int kn = (k4 < 63) ? k4 + 1 : 63;
            float4 wan = w0v[kn], wbn = w1v[kn];
            float4 xv[BM];
            #pragma unroll
            for (int b = 0; b < BM; ++b) xv[b] = xsv[b * 64 + k4];
            #pragma unroll
            for (int b = 0; b < BM; ++b) {
                acc0[b] = fmaf(xv[b].x, wa.x, acc0[b]);
                acc0[b] = fmaf(xv[b].y, wa.y, acc0[b]);
                acc0[b] = fmaf(xv[b].z, wa.z, acc0[b]);
                acc0[b] = fmaf(xv[b].w, wa.w, acc0[b]);
                acc1[b] = fmaf(xv[b].x, wb.x, acc1[b]);
                acc1[b] = fmaf(xv[b].y, wb.y, acc1[b]);
                acc1[b] = fmaf(xv[b].z, wb.z, acc1[b]);
                acc1[b] = fmaf(xv[b].w, wb.w, acc1[b]);
            }
            wa = wan; wb = wbn;
        }
        #pragma unroll
        for (int b = 0; b < BM; ++b) {
            float2* dst = (float2*)&h1s[b * LDS_H_STRIDE + h0];
            *dst = make_float2(acc0[b], acc1[b]);
        }
    }
    __syncthreads();

    {
        const int l   = tid & 63;
        const int w   = tid >> 6;
        const int l15 = l & 15;
        const int b_local = w * 4 + (l >> 4);
        const int row = row0 + b_local;

        float hv[32], w0r[32], w1r[32], mem[32];
        #pragma unroll
        for (int j = 0; j < 32; ++j) {
            const int h = l15 + j * 16;
            hv[j]  = h1s[b_local * LDS_H_STRIDE + h];
            w0r[j] = W2[h];
            w1r[j] = W2[512 + h];
            mem[j] = 0.0f;
        }
        const float bb0 = b2[0], bb1 = b2[1];
        const int   T   = tsp[0];

        float c0 = 0.0f, c1 = 0.0f;
        for (int t = 0; t < T; ++t) {
            float a0 = 0.0f, a1 = 0.0f, a0b = 0.0f, a1b = 0.0f;
            #pragma unroll
            for (int j = 0; j < 32; j += 2) {
                float m0 = __fadd_rn(__fmul_rn(0.9f, mem[j]),     hv[j]);
                float m1 = __fadd_rn(__fmul_rn(0.9f, mem[j + 1]), hv[j + 1]);
                float s0 = (m0 > 1.0f) ? 1.0f : 0.0f;
                float s1 = (m1 > 1.0f) ? 1.0f : 0.0f;
                mem[j]     = m0 - s0;
                mem[j + 1] = m1 - s1;
                a0  = fmaf(s0, w0r[j],     a0);
                a1  = fmaf(s0, w1r[j],     a1);
                a0b = fmaf(s1, w0r[j + 1], a0b);
                a1b = fmaf(s1, w1r[j + 1], a1b);
            }
            a0 += a0b; a1 += a1b;
            a0 = dpp_add<0x121>(a0); a1 = dpp_add<0x121>(a1);
            a0 = dpp_add<0x122>(a0); a1 = dpp_add<0x122>(a1);
            a0 = dpp_add<0x124>(a0); a1 = dpp_add<0x124>(a1);
            a0 = dpp_add<0x128>(a0); a1 = dpp_add<0x128>(a1);
            c0 += ((a0 + bb0) > 0.0f) ? 1.0f : 0.0f;
            c1 += ((a1 + bb1) > 0.0f) ? 1.0f : 0.0f;
        }

        if (l15 == 0) {
            const float ft = (float)T;
            float2* dst = (float2*)(out + (size_t)row * 2);
            *dst = make_float2(c0 / ft, c1 / ft);
        }
    }
}

extern "C" void kernel_launch(void* const* d_in, const int* in_sizes, int n_in,
                              void* d_out, int out_size, void* d_ws, size_t ws_size,
                              hipStream_t stream) {
    const float* x   = (const float*)d_in[0];
    const float* W1  = (const float*)d_in[1];
    const float* b1  = (const float*)d_in[2];
    const float* W2  = (const float*)d_in[3];
    const float* b2  = (const float*)d_in[4];
    const int*   tsp = (const int*)d_in[5];
    float*       out = (float*)d_out;

    const int B = in_sizes[0] / 256;                     // 4096
    const size_t need = (size_t)B * 512 * sizeof(float); // 8 MiB

    if (ws_size >= need) {
        float* h1ws = (float*)d_ws;
        snn_fc1_kernel<<<dim3(B / TM, 512 / TN), dim3(256), 0, stream>>>(
            x, W1, b1, h1ws);
        snn_lif_kernel<<<dim3(B / 8), dim3(256), 0, stream>>>(
            h1ws, W2, b2, tsp, out);
    } else {
        snn_fused_kernel<<<dim3(B / BM), dim3(256), 0, stream>>>(
            x, W1, b1, W2, b2, tsp, out);
    }
}

// Round 10
// 57.677 us; speedup vs baseline: 2.5764x; 1.0119x over previous
//
#include <hip/hip_runtime.h>

// SNN binary classifier, two-kernel split. B=4096, D=256, H=512, O=2, T=100.
//
// R9 post-mortem: LIF ~40us at 2 waves/SIMD is dependency-latency-bound
// (serial membrane -> 5-stage DPP chain -> c-update per step; occupancy is
// pinned at 2048 waves by the 2-rows/wave decomposition). R10: software-
// pipeline the t-loop by 2 — membrane(t+1) is independent of reduce(t), and
// the two steps' reduce trees (4 chains: A0,A1,B0,B1) interleave to fill DPP
// hazard slots. ZERO arithmetic change vs R9 (absmax 0.01171875 is exactly
// one bf16-quantized spike flip on the worst element — no rounding-order
// perturbations allowed).
// fc1: byte-identical to R7-R9 (h1 bit-identical to all passing rounds).

template <int CTRL>
__device__ __forceinline__ float dpp_add(float v) {
    int x = __builtin_amdgcn_update_dpp(0, __builtin_bit_cast(int, v),
                                        CTRL, 0xF, 0xF, false);
    return v + __builtin_bit_cast(float, x);
}

// ---------------- Kernel A: fc1 GEMM (LDS-tiled, byte-identical to R7) ----------------
#define TM 64
#define TN 64
#define TK 64
#define XS_STRIDE4 17   // float4 units per x row (16 + 1 pad)
#define WS_STRIDE  68   // floats per k row (64 + 4 pad, 16B aligned)

__global__ __launch_bounds__(256)
__attribute__((amdgpu_waves_per_eu(2, 4)))
void snn_fc1_kernel(const float* __restrict__ x,   // [4096,256]
                    const float* __restrict__ W1,  // [512,256]
                    const float* __restrict__ b1,  // [512]
                    float* __restrict__ h1ws)      // [4096,512]
{
    __shared__ float4 xs4[TM * XS_STRIDE4];   // 17.0 KiB
    __shared__ float  wsf[TK * WS_STRIDE];    // 17.0 KiB

    const int tid  = threadIdx.x;
    const int row0 = blockIdx.x * TM;
    const int col0 = blockIdx.y * TN;

    const int tx = tid & 15;
    const int ty = tid >> 4;

    float acc[4][4];
    {
        const float4 bv = ((const float4*)b1)[(col0 >> 2) + tx];
        #pragma unroll
        for (int r = 0; r < 4; ++r) {
            acc[r][0] = bv.x; acc[r][1] = bv.y;
            acc[r][2] = bv.z; acc[r][3] = bv.w;
        }
    }

    const float4* xg = (const float4*)x;   // [4096][64]
    const float4* wg = (const float4*)W1;  // [512][64]

    for (int chunk = 0; chunk < 4; ++chunk) {
        const int k0q = chunk * 16;

        #pragma unroll
        for (int i = 0; i < 4; ++i) {
            const int idx = tid + i * 256;
            const int row = idx >> 4;
            const int q   = idx & 15;
            xs4[row * XS_STRIDE4 + q] =
                xg[(size_t)(row0 + row) * 64 + k0q + q];
        }
        #pragma unroll
        for (int i = 0; i < 4; ++i) {
            const int idx = tid + i * 256;
            const int q   = idx & 15;
            const int c   = idx >> 4;
            const float4 wv4 = wg[(size_t)(col0 + c) * 64 + k0q + q];
            wsf[(q * 4 + 0) * WS_STRIDE + c] = wv4.x;
            wsf[(q * 4 + 1) * WS_STRIDE + c] = wv4.y;
            wsf[(q * 4 + 2) * WS_STRIDE + c] = wv4.z;
            wsf[(q * 4 + 3) * WS_STRIDE + c] = wv4.w;
        }
        __syncthreads();

        #pragma unroll
        for (int k4 = 0; k4 < 16; ++k4) {
            float4 xv[4], wv[4];
            #pragma unroll
            for (int r = 0; r < 4; ++r)
                xv[r] = xs4[(ty * 4 + r) * XS_STRIDE4 + k4];
            #pragma unroll
            for (int kk = 0; kk < 4; ++kk)
                wv[kk] = *(const float4*)&wsf[(k4 * 4 + kk) * WS_STRIDE + tx * 4];
            #pragma unroll
            for (int kk = 0; kk < 4; ++kk) {
                const float xk0 = xv[0][kk], xk1 = xv[1][kk];
                const float xk2 = xv[2][kk], xk3 = xv[3][kk];
                #pragma unroll
                for (int cc = 0; cc < 4; ++cc) {
                    const float w = wv[kk][cc];
                    acc[0][cc] = fmaf(xk0, w, acc[0][cc]);
                    acc[1][cc] = fmaf(xk1, w, acc[1][cc]);
                    acc[2][cc] = fmaf(xk2, w, acc[2][cc]);
                    acc[3][cc] = fmaf(xk3, w, acc[3][cc]);
                }
            }
        }
        __syncthreads();
    }

    #pragma unroll
    for (int r = 0; r < 4; ++r) {
        float4* dst = (float4*)&h1ws[(size_t)(row0 + ty * 4 + r) * 512
                                     + col0 + tx * 4];
        *dst = make_float4(acc[r][0], acc[r][1], acc[r][2], acc[r][3]);
    }
}

// ---------------- Kernel B: LIF, 2 rows/wave + compaction + t-unroll-2 ----------------
#define DEAD_CUT 0.0999f   // provably-never-spikes bound is 0.0999975

template <int E>
__device__ __forceinline__ void lif_body2(const float2* __restrict__ cl, int l31,
                                          const float* __restrict__ W2,
                                          float bb0, float bb1, int T,
                                          float* __restrict__ dst, bool writer)
{
    float hv[E], w0r[E], w1r[E], mem[E];
    #pragma unroll
    for (int j = 0; j < E; ++j) {
        const float2 p = cl[j * 32 + l31];
        hv[j] = p.x;
        const int idx = __float_as_int(p.y);
        w0r[j] = W2[idx];
        w1r[j] = W2[512 + idx];
        mem[j] = 0.0f;
    }
    float c0 = 0.0f, c1 = 0.0f;

    // one membrane step: identical algebra to R8/R9 (non-fused mul+add)
    auto memb = [&](float& A0, float& A1) {
        float a0 = 0.0f, a1 = 0.0f, a0b = 0.0f, a1b = 0.0f;
        #pragma unroll
        for (int j = 0; j < E; ++j) {
            const float m = __fadd_rn(__fmul_rn(0.9f, mem[j]), hv[j]);
            const float s = (m > 1.0f) ? 1.0f : 0.0f;
            mem[j] = m - s;
            if ((j & 1) == 0) { a0  = fmaf(s, w0r[j], a0);  a1  = fmaf(s, w1r[j], a1);  }
            else              { a0b = fmaf(s, w0r[j], a0b); a1b = fmaf(s, w1r[j], a1b); }
        }
        A0 = a0 + a0b; A1 = a1 + a1b;
    };

    int t = 0;
    for (; t + 1 < T; t += 2) {
        float aA0, aA1, aB0, aB1;
        memb(aA0, aA1);          // step t   (independent of step t's reduce)
        memb(aB0, aB1);          // step t+1 (depends only on mem[], done above)
        // 4 independent DPP chains interleaved to fill hazard slots.
        // Per-value tree identical to R9: ror1/2/4/8 + row_bcast15.
        aA0 = dpp_add<0x121>(aA0); aA1 = dpp_add<0x121>(aA1);
        aB0 = dpp_add<0x121>(aB0); aB1 = dpp_add<0x121>(aB1);
        aA0 = dpp_add<0x122>(aA0); aA1 = dpp_add<0x122>(aA1);
        aB0 = dpp_add<0x122>(aB0); aB1 = dpp_add<0x122>(aB1);
        aA0 = dpp_add<0x124>(aA0); aA1 = dpp_add<0x124>(aA1);
        aB0 = dpp_add<0x124>(aB0); aB1 = dpp_add<0x124>(aB1);
        aA0 = dpp_add<0x128>(aA0); aA1 = dpp_add<0x128>(aA1);
        aB0 = dpp_add<0x128>(aB0); aB1 = dpp_add<0x128>(aB1);
        aA0 = dpp_add<0x142>(aA0); aA1 = dpp_add<0x142>(aA1);
        aB0 = dpp_add<0x142>(aB0); aB1 = dpp_add<0x142>(aB1);
        // lanes 16-31 row A sum / lanes 48-63 row B sum (per 32-half)
        c0 += ((aA0 + bb0) > 0.0f) ? 1.0f : 0.0f;
        c1 += ((aA1 + bb1) > 0.0f) ? 1.0f : 0.0f;
        c0 += ((aB0 + bb0) > 0.0f) ? 1.0f : 0.0f;
        c1 += ((aB1 + bb1) > 0.0f) ? 1.0f : 0.0f;
    }
    if (t < T) {
        float a0, a1;
        memb(a0, a1);
        a0 = dpp_add<0x121>(a0); a1 = dpp_add<0x121>(a1);
        a0 = dpp_add<0x122>(a0); a1 = dpp_add<0x122>(a1);
        a0 = dpp_add<0x124>(a0); a1 = dpp_add<0x124>(a1);
        a0 = dpp_add<0x128>(a0); a1 = dpp_add<0x128>(a1);
        a0 = dpp_add<0x142>(a0); a1 = dpp_add<0x142>(a1);
        c0 += ((a0 + bb0) > 0.0f) ? 1.0f : 0.0f;
        c1 += ((a1 + bb1) > 0.0f) ? 1.0f : 0.0f;
    }

    if (writer) {
        const float ft = (float)T;
        *(float2*)dst = make_float2(c0 / ft, c1 / ft);
    }
}

__global__ __launch_bounds__(256)
__attribute__((amdgpu_waves_per_eu(2, 4)))
void snn_lif_kernel(const float* __restrict__ h1ws, // [4096,512]
                    const float* __restrict__ W2,   // [2,512]
                    const float* __restrict__ b2,   // [2]
                    const int* __restrict__ tsp,    // [1]
                    float* __restrict__ out)        // [4096,2]
{
    __shared__ float2 comp[8][512];   // 32 KiB: per-row compacted (h1, idx)

    const int tid  = threadIdx.x;
    const int l    = tid & 63;
    const int wid  = tid >> 6;
    const int half = l >> 5;          // 0: row A, 1: row B
    const int l31  = l & 31;
    const int rowA = blockIdx.x * 8 + wid * 2;

    // per-row zero-fill + 64-lane ballot compaction (proven R8 code), x2 rows
    unsigned bases[2];
    #pragma unroll
    for (int r = 0; r < 2; ++r) {
        float2* cw = comp[wid * 2 + r];
        #pragma unroll
        for (int j = 0; j < 8; ++j)
            cw[j * 64 + l] = make_float2(0.0f, __int_as_float(0));
        const float* hrow = h1ws + (size_t)(rowA + r) * 512;
        unsigned base = 0;
        #pragma unroll
        for (int j = 0; j < 8; ++j) {
            const int h = j * 64 + l;
            const float v = hrow[h];
            const bool live = v > DEAD_CUT;
            const unsigned long long m = __ballot(live);
            const unsigned pos = (unsigned)__popcll(m & ((1ull << l) - 1ull));
            if (live) cw[base + pos] = make_float2(v, __int_as_float(h));
            base += (unsigned)__popcll(m);
        }
        bases[r] = base;
    }
    // comp is wave-private (same wave writes & reads) -> no __syncthreads

    const float bb0 = b2[0], bb1 = b2[1];
    const int   T   = tsp[0];
    const int   row = rowA + half;
    float* dst = out + (size_t)row * 2;
    const bool writer = (l31 == 16);      // lanes 16 (row A) and 48 (row B)

    const unsigned mx = bases[0] > bases[1] ? bases[0] : bases[1];
    int trips = (int)((mx + 31u) >> 5);
    if (trips < 1) trips = 1;
    const float2* cl = comp[wid * 2 + half];

    switch (trips) {
        case 1:  lif_body2<1>(cl, l31, W2, bb0, bb1, T, dst, writer); break;
        case 2:  lif_body2<2>(cl, l31, W2, bb0, bb1, T, dst, writer); break;
        case 3:  lif_body2<3>(cl, l31, W2, bb0, bb1, T, dst, writer); break;
        case 4:  lif_body2<4>(cl, l31, W2, bb0, bb1, T, dst, writer); break;
        case 5:  lif_body2<5>(cl, l31, W2, bb0, bb1, T, dst, writer); break;
        case 6:  lif_body2<6>(cl, l31, W2, bb0, bb1, T, dst, writer); break;
        case 7:  lif_body2<7>(cl, l31, W2, bb0, bb1, T, dst, writer); break;
        case 8:  lif_body2<8>(cl, l31, W2, bb0, bb1, T, dst, writer); break;
        case 9:  lif_body2<9>(cl, l31, W2, bb0, bb1, T, dst, writer); break;
        case 10: lif_body2<10>(cl, l31, W2, bb0, bb1, T, dst, writer); break;
        case 11: lif_body2<11>(cl, l31, W2, bb0, bb1, T, dst, writer); break;
        case 12: lif_body2<12>(cl, l31, W2, bb0, bb1, T, dst, writer); break;
        case 13: lif_body2<13>(cl, l31, W2, bb0, bb1, T, dst, writer); break;
        case 14: lif_body2<14>(cl, l31, W2, bb0, bb1, T, dst, writer); break;
        case 15: lif_body2<15>(cl, l31, W2, bb0, bb1, T, dst, writer); break;
        default: lif_body2<16>(cl, l31, W2, bb0, bb1, T, dst, writer); break;
    }
}

// ---------------- Fallback: proven R1 fused kernel ----------------
#define BM 16
#define LDS_H_STRIDE 520

__global__ __launch_bounds__(256, 1) void snn_fused_kernel(
    const float* __restrict__ x, const float* __restrict__ W1,
    const float* __restrict__ b1, const float* __restrict__ W2,
    const float* __restrict__ b2, const int* __restrict__ tsp,
    float* __restrict__ out)
{
    __shared__ float xs[BM * 256];
    __shared__ float h1s[BM * LDS_H_STRIDE];

    const int tid  = threadIdx.x;
    const int row0 = blockIdx.x * BM;

    {
        const float4* xg  = (const float4*)(x + (size_t)row0 * 256);
        float4*       xsv = (float4*)xs;
        #pragma unroll
        for (int i = 0; i < 4; ++i)
            xsv[i * 256 + tid] = xg[i * 256 + tid];
    }
    __syncthreads();

    {
        const int h0 = tid * 2;
        float acc0[BM], acc1[BM];
        const float bia0 = b1[h0], bia1 = b1[h0 + 1];
        #pragma unroll
        for (int b = 0; b < BM; ++b) { acc0[b] = bia0; acc1[b] = bia1; }
        const float4* w0v = (const float4*)(W1 + (size_t)h0 * 256);
        const float4* w1v = (const float4*)(W1 + (size_t)(h0 + 1) * 256);
        const float4* xsv = (const float4*)xs;
        float4 wa = w0v[0], wb = w1v[0];
        #pragma unroll 1
        for (int k4 = 0; k4 < 64; ++k4) {
            const int kn = (k4 < 63) ? k4 + 1 : 63;
            float4 wan = w0v[kn], wbn = w1v[kn];
            float4 xv[BM];
            #pragma unroll
            for (int b = 0; b < BM; ++b) xv[b] = xsv[b * 64 + k4];
            #pragma unroll
            for (int b = 0; b < BM; ++b) {
                acc0[b] = fmaf(xv[b].x, wa.x, acc0[b]);
                acc0[b] = fmaf(xv[b].y, wa.y, acc0[b]);
                acc0[b] = fmaf(xv[b].z, wa.z, acc0[b]);
                acc0[b] = fmaf(xv[b].w, wa.w, acc0[b]);
                acc1[b] = fmaf(xv[b].x, wb.x, acc1[b]);
                acc1[b] = fmaf(xv[b].y, wb.y, acc1[b]);
                acc1[b] = fmaf(xv[b].z, wb.z, acc1[b]);
                acc1[b] = fmaf(xv[b].w, wb.w, acc1[b]);
            }
            wa = wan; wb = wbn;
        }
        #pragma unroll
        for (int b = 0; b < BM; ++b) {
            float2* dst = (float2*)&h1s[b * LDS_H_STRIDE + h0];
            *dst = make_float2(acc0[b], acc1[b]);
        }
    }
    __syncthreads();

    {
        const int l   = tid & 63;
        const int w   = tid >> 6;
        const int l15 = l & 15;
        const int b_local = w * 4 + (l >> 4);
        const int row = row0 + b_local;

        float hv[32], w0r[32], w1r[32], mem[32];
        #pragma unroll
        for (int j = 0; j < 32; ++j) {
            const int h = l15 + j * 16;
            hv[j]  = h1s[b_local * LDS_H_STRIDE + h];
            w0r[j] = W2[h];
            w1r[j] = W2[512 + h];
            mem[j] = 0.0f;
        }
        const float bb0 = b2[0], bb1 = b2[1];
        const int   T   = tsp[0];

        float c0 = 0.0f, c1 = 0.0f;
        for (int t = 0; t < T; ++t) {
            float a0 = 0.0f, a1 = 0.0f, a0b = 0.0f, a1b = 0.0f;
            #pragma unroll
            for (int j = 0; j < 32; j += 2) {
                float m0 = __fadd_rn(__fmul_rn(0.9f, mem[j]),     hv[j]);
                float m1 = __fadd_rn(__fmul_rn(0.9f, mem[j + 1]), hv[j + 1]);
                float s0 = (m0 > 1.0f) ? 1.0f : 0.0f;
                float s1 = (m1 > 1.0f) ? 1.0f : 0.0f;
                mem[j]     = m0 - s0;
                mem[j + 1] = m1 - s1;
                a0  = fmaf(s0, w0r[j],     a0);
                a1  = fmaf(s0, w1r[j],     a1);
                a0b = fmaf(s1, w0r[j + 1], a0b);
                a1b = fmaf(s1, w1r[j + 1], a1b);
            }
            a0 += a0b; a1 += a1b;
            a0 = dpp_add<0x121>(a0); a1 = dpp_add<0x121>(a1);
            a0 = dpp_add<0x122>(a0); a1 = dpp_add<0x122>(a1);
            a0 = dpp_add<0x124>(a0); a1 = dpp_add<0x124>(a1);
            a0 = dpp_add<0x128>(a0); a1 = dpp_add<0x128>(a1);
            c0 += ((a0 + bb0) > 0.0f) ? 1.0f : 0.0f;
            c1 += ((a1 + bb1) > 0.0f) ? 1.0f : 0.0f;
        }

        if (l15 == 0) {
            const float ft = (float)T;
            float2* dst = (float2*)(out + (size_t)row * 2);
            *dst = make_float2(c0 / ft, c1 / ft);
        }
    }
}

extern "C" void kernel_launch(void* const* d_in, const int* in_sizes, int n_in,
                              void* d_out, int out_size, void* d_ws, size_t ws_size,
                              hipStream_t stream) {
    const float* x   = (const float*)d_in[0];
    const float* W1  = (const float*)d_in[1];
    const float* b1  = (const float*)d_in[2];
    const float* W2  = (const float*)d_in[3];
    const float* b2  = (const float*)d_in[4];
    const int*   tsp = (const int*)d_in[5];
    float*       out = (float*)d_out;

    const int B = in_sizes[0] / 256;                     // 4096
    const size_t need = (size_t)B * 512 * sizeof(float); // 8 MiB

    if (ws_size >= need) {
        float* h1ws = (float*)d_ws;
        snn_fc1_kernel<<<dim3(B / TM, 512 / TN), dim3(256), 0, stream>>>(
            x, W1, b1, h1ws);
        snn_lif_kernel<<<dim3(B / 8), dim3(256), 0, stream>>>(
            h1ws, W2, b2, tsp, out);
    } else {
        snn_fused_kernel<<<dim3(B / BM), dim3(256), 0, stream>>>(
            x, W1, b1, W2, b2, tsp, out);
    }
}